// Round 1
// baseline (972.071 us; speedup 1.0000x reference)
//
#include <hip/hip_runtime.h>

#define NN 100000
#define NE 1600000
#define EPSF 1e-5f

// ---------------- graph preprocessing ----------------

__global__ __launch_bounds__(256) void deg_count(const int* __restrict__ ei, const float* __restrict__ ew,
                                                 float* __restrict__ deg, int* __restrict__ cnt, int E) {
    int e = blockIdx.x * 256 + threadIdx.x;
    if (e < E) {
        int d = ei[E + e];
        atomicAdd(&deg[d], ew[e]);
        atomicAdd(&cnt[d], 1);
    }
}

__global__ __launch_bounds__(256) void to_dinv(float* deg, int n) {
    int i = blockIdx.x * 256 + threadIdx.x;
    if (i < n) deg[i] = rsqrtf(deg[i] + 1.0f);
}

// exclusive scan of cnt[0..n) -> out, block partial sums -> blk (blocks of 1024)
__global__ __launch_bounds__(256) void scan1(const int* __restrict__ cnt, int* __restrict__ out,
                                             int* __restrict__ blk, int n) {
    __shared__ int s[256];
    int t = threadIdx.x;
    int base = blockIdx.x * 1024 + t * 4;
    int v0 = base + 0 < n ? cnt[base + 0] : 0;
    int v1 = base + 1 < n ? cnt[base + 1] : 0;
    int v2 = base + 2 < n ? cnt[base + 2] : 0;
    int v3 = base + 3 < n ? cnt[base + 3] : 0;
    s[t] = v0 + v1 + v2 + v3;
    __syncthreads();
    for (int off = 1; off < 256; off <<= 1) {
        int x = (t >= off) ? s[t - off] : 0;
        __syncthreads();
        s[t] += x;
        __syncthreads();
    }
    int excl = t ? s[t - 1] : 0;
    if (t == 255) blk[blockIdx.x] = s[255];
    if (base + 0 < n) out[base + 0] = excl;
    if (base + 1 < n) out[base + 1] = excl + v0;
    if (base + 2 < n) out[base + 2] = excl + v0 + v1;
    if (base + 3 < n) out[base + 3] = excl + v0 + v1 + v2;
}

__global__ void scan2(int* blk, int nb) {
    __shared__ int s[256];
    int t = threadIdx.x;
    s[t] = t < nb ? blk[t] : 0;
    __syncthreads();
    for (int off = 1; off < 256; off <<= 1) {
        int x = (t >= off) ? s[t - off] : 0;
        __syncthreads();
        s[t] += x;
        __syncthreads();
    }
    if (t < nb) blk[t] = t ? s[t - 1] : 0;
}

__global__ __launch_bounds__(256) void scan3(int* __restrict__ row, const int* __restrict__ blk, int n, int Etot) {
    int i = blockIdx.x * 256 + threadIdx.x;
    if (i < n) row[i] += blk[i >> 10];
    if (i == 0) row[n] = Etot;
}

__global__ __launch_bounds__(256) void fill_csr(const int* __restrict__ ei, const float* __restrict__ ew,
                                                const float* __restrict__ dinv, int* __restrict__ cur,
                                                int* __restrict__ csrs, float* __restrict__ csrw, int E) {
    int e = blockIdx.x * 256 + threadIdx.x;
    if (e < E) {
        int s = ei[e], d = ei[E + e];
        float w = ew[e] * dinv[s] * dinv[d];
        int pos = atomicAdd(&cur[d], 1);
        csrs[pos] = s;
        csrw[pos] = w;
    }
}

// ---------------- GEMM: Y[n,128] = X[n,128] @ W[128,128] ----------------

__global__ __launch_bounds__(256) void gemm128(const float* __restrict__ X, const float* __restrict__ W,
                                               float* __restrict__ Y, int n) {
    __shared__ float Wl[128 * 128];  // 64 KB
    for (int i = threadIdx.x * 4; i < 128 * 128; i += 1024)
        *(float4*)&Wl[i] = *(const float4*)&W[i];
    __syncthreads();
    int wave = __builtin_amdgcn_readfirstlane(threadIdx.x >> 6);
    int lane = threadIdx.x & 63;
    int nw = gridDim.x * 4;
    for (int r0 = (blockIdx.x * 4 + wave) * 8; r0 < n; r0 += nw * 8) {
        float2 acc[8];
#pragma unroll
        for (int i = 0; i < 8; i++) acc[i] = make_float2(0.f, 0.f);
        int nr = n - r0; if (nr > 8) nr = 8;
        if (nr == 8) {
            const float* __restrict__ xr = X + (size_t)r0 * 128;
#pragma unroll 4
            for (int k = 0; k < 128; k += 4) {
                float2 w0 = *(const float2*)&Wl[(k + 0) * 128 + lane * 2];
                float2 w1 = *(const float2*)&Wl[(k + 1) * 128 + lane * 2];
                float2 w2 = *(const float2*)&Wl[(k + 2) * 128 + lane * 2];
                float2 w3 = *(const float2*)&Wl[(k + 3) * 128 + lane * 2];
#pragma unroll
                for (int rr = 0; rr < 8; rr++) {
                    float4 xk = *(const float4*)&xr[rr * 128 + k];
                    acc[rr].x += xk.x * w0.x; acc[rr].y += xk.x * w0.y;
                    acc[rr].x += xk.y * w1.x; acc[rr].y += xk.y * w1.y;
                    acc[rr].x += xk.z * w2.x; acc[rr].y += xk.z * w2.y;
                    acc[rr].x += xk.w * w3.x; acc[rr].y += xk.w * w3.y;
                }
            }
#pragma unroll
            for (int rr = 0; rr < 8; rr++)
                *(float2*)&Y[(size_t)(r0 + rr) * 128 + lane * 2] = acc[rr];
        } else {
            for (int rr = 0; rr < nr; rr++) {
                const float* xr = X + (size_t)(r0 + rr) * 128;
                float2 a = make_float2(0.f, 0.f);
                for (int k = 0; k < 128; k++) {
                    float xk = xr[k];
                    float2 w = *(const float2*)&Wl[k * 128 + lane * 2];
                    a.x += xk * w.x; a.y += xk * w.y;
                }
                *(float2*)&Y[(size_t)(r0 + rr) * 128 + lane * 2] = a;
            }
        }
    }
}

// ---------------- aggregation: OUT[d] = sum_e nrm*XW[src] + dinv^2*XW[d] + b ----------------

__global__ __launch_bounds__(256) void aggregate(const float* __restrict__ XW, const int* __restrict__ row,
                                                 const int* __restrict__ csrs, const float* __restrict__ csrw,
                                                 const float* __restrict__ dinv, const float* __restrict__ bias,
                                                 float* __restrict__ OUT, int n) {
    int wave = __builtin_amdgcn_readfirstlane(threadIdx.x >> 6);
    int lane = threadIdx.x & 63;
    int node = blockIdx.x * 4 + wave;
    if (node >= n) return;
    int beg = row[node], end = row[node + 1];
    float ax = 0.f, ay = 0.f;
    int e = beg;
    for (; e + 1 < end; e += 2) {
        int s0 = csrs[e], s1 = csrs[e + 1];
        float w0 = csrw[e], w1 = csrw[e + 1];
        float2 v0 = *(const float2*)&XW[(size_t)s0 * 128 + lane * 2];
        float2 v1 = *(const float2*)&XW[(size_t)s1 * 128 + lane * 2];
        ax += w0 * v0.x + w1 * v1.x;
        ay += w0 * v0.y + w1 * v1.y;
    }
    if (e < end) {
        int s0 = csrs[e];
        float w0 = csrw[e];
        float2 v0 = *(const float2*)&XW[(size_t)s0 * 128 + lane * 2];
        ax += w0 * v0.x; ay += w0 * v0.y;
    }
    float di = dinv[node], sl = di * di;
    float2 vs = *(const float2*)&XW[(size_t)node * 128 + lane * 2];
    float2 b = *(const float2*)&bias[lane * 2];
    float2 o;
    o.x = ax + sl * vs.x + b.x;
    o.y = ay + sl * vs.y + b.y;
    *(float2*)&OUT[(size_t)node * 128 + lane * 2] = o;
}

// ---------------- BatchNorm ----------------

__global__ __launch_bounds__(256) void bn_stats(const float* __restrict__ H, float* __restrict__ part, int n) {
    int wave = threadIdx.x >> 6;
    int lane = threadIdx.x & 63;
    float2 s = make_float2(0.f, 0.f), q = make_float2(0.f, 0.f);
    for (int r = blockIdx.x * 4 + wave; r < n; r += gridDim.x * 4) {
        float2 v = *(const float2*)&H[(size_t)r * 128 + lane * 2];
        s.x += v.x; s.y += v.y;
        q.x += v.x * v.x; q.y += v.y * v.y;
    }
    __shared__ float2 reds[4][64];
    __shared__ float2 redq[4][64];
    reds[wave][lane] = s;
    redq[wave][lane] = q;
    __syncthreads();
    if (threadIdx.x < 64) {
        int l = threadIdx.x;
        float2 S = make_float2(0.f, 0.f), Q = make_float2(0.f, 0.f);
#pragma unroll
        for (int w = 0; w < 4; w++) {
            S.x += reds[w][l].x; S.y += reds[w][l].y;
            Q.x += redq[w][l].x; Q.y += redq[w][l].y;
        }
        part[blockIdx.x * 256 + l * 2 + 0] = S.x;
        part[blockIdx.x * 256 + l * 2 + 1] = S.y;
        part[blockIdx.x * 256 + 128 + l * 2 + 0] = Q.x;
        part[blockIdx.x * 256 + 128 + l * 2 + 1] = Q.y;
    }
}

__global__ void bn_final(const float* __restrict__ part, const float* __restrict__ gamma,
                         const float* __restrict__ beta, float* __restrict__ stats, int nb, float invN) {
    int c = threadIdx.x;
    if (c >= 128) return;
    float s = 0.f, q = 0.f;
    for (int b = 0; b < nb; b++) {
        s += part[b * 256 + c];
        q += part[b * 256 + 128 + c];
    }
    float mu = s * invN;
    float var = q * invN - mu * mu;
    float sc = gamma[c] * rsqrtf(var + EPSF);
    stats[c] = sc;
    stats[128 + c] = beta[c] - mu * sc;
}

__global__ __launch_bounds__(256) void bn_apply(const float* __restrict__ H, const float* __restrict__ stats,
                                                float* __restrict__ H1v, int total) {
    __shared__ float s[256];
    s[threadIdx.x] = stats[threadIdx.x];
    __syncthreads();
    int stride = gridDim.x * 256 * 4;
    for (int i = (blockIdx.x * 256 + threadIdx.x) * 4; i < total; i += stride) {
        float4 v = *(const float4*)&H[i];
        int c = i & 127;
        v.x = fmaxf(v.x * s[c + 0] + s[128 + c + 0], 0.f);
        v.y = fmaxf(v.y * s[c + 1] + s[128 + c + 1], 0.f);
        v.z = fmaxf(v.z * s[c + 2] + s[128 + c + 2], 0.f);
        v.w = fmaxf(v.w * s[c + 3] + s[128 + c + 3], 0.f);
        *(float4*)&H1v[i] = v;
    }
}

// ---------------- final: OUT[n,64] = max(H1,H2) @ Wf + bf ----------------

__global__ __launch_bounds__(256) void final_proj(const float* __restrict__ H1v, const float* __restrict__ H2v,
                                                  const float* __restrict__ Wf, const float* __restrict__ bf,
                                                  float* __restrict__ OUT, int n) {
    __shared__ float Wl[128 * 64];  // 32 KB
    for (int i = threadIdx.x * 4; i < 128 * 64; i += 1024)
        *(float4*)&Wl[i] = *(const float4*)&Wf[i];
    __syncthreads();
    int wave = __builtin_amdgcn_readfirstlane(threadIdx.x >> 6);
    int lane = threadIdx.x & 63;
    float bfl = bf[lane];
    int nw = gridDim.x * 4;
    for (int r0 = (blockIdx.x * 4 + wave) * 8; r0 < n; r0 += nw * 8) {
        float acc[8];
#pragma unroll
        for (int i = 0; i < 8; i++) acc[i] = 0.f;
        int nr = n - r0; if (nr > 8) nr = 8;
        if (nr == 8) {
            const float* __restrict__ x1 = H1v + (size_t)r0 * 128;
            const float* __restrict__ x2 = H2v + (size_t)r0 * 128;
#pragma unroll 2
            for (int k = 0; k < 128; k += 4) {
                float w0 = Wl[(k + 0) * 64 + lane];
                float w1 = Wl[(k + 1) * 64 + lane];
                float w2 = Wl[(k + 2) * 64 + lane];
                float w3 = Wl[(k + 3) * 64 + lane];
#pragma unroll
                for (int rr = 0; rr < 8; rr++) {
                    float4 a = *(const float4*)&x1[rr * 128 + k];
                    float4 c = *(const float4*)&x2[rr * 128 + k];
                    acc[rr] += fmaxf(a.x, c.x) * w0 + fmaxf(a.y, c.y) * w1 +
                               fmaxf(a.z, c.z) * w2 + fmaxf(a.w, c.w) * w3;
                }
            }
#pragma unroll
            for (int rr = 0; rr < 8; rr++)
                OUT[(size_t)(r0 + rr) * 64 + lane] = acc[rr] + bfl;
        } else {
            for (int rr = 0; rr < nr; rr++) {
                const float* x1 = H1v + (size_t)(r0 + rr) * 128;
                const float* x2 = H2v + (size_t)(r0 + rr) * 128;
                float a = 0.f;
                for (int k = 0; k < 128; k++) a += fmaxf(x1[k], x2[k]) * Wl[k * 64 + lane];
                OUT[(size_t)(r0 + rr) * 64 + lane] = a + bfl;
            }
        }
    }
}

// ---------------- launch ----------------

extern "C" void kernel_launch(void* const* d_in, const int* in_sizes, int n_in,
                              void* d_out, int out_size, void* d_ws, size_t ws_size,
                              hipStream_t stream) {
    const float* x     = (const float*)d_in[0];
    const int*   ei    = (const int*)  d_in[1];
    const float* ew    = (const float*)d_in[2];
    const float* W1    = (const float*)d_in[3];
    const float* b1    = (const float*)d_in[4];
    const float* gamma = (const float*)d_in[5];
    const float* beta  = (const float*)d_in[6];
    const float* W2    = (const float*)d_in[7];
    const float* b2    = (const float*)d_in[8];
    const float* Wf    = (const float*)d_in[9];
    const float* bf    = (const float*)d_in[10];
    float* out = (float*)d_out;

    char* ws = (char*)d_ws;
    size_t off = 0;
    auto alloc = [&](size_t bytes) {
        void* p = ws + off;
        off += (bytes + 1023) & ~(size_t)1023;
        return p;
    };
    float* XW   = (float*)alloc((size_t)NN * 128 * 4);  // xw / xw2
    float* H    = (float*)alloc((size_t)NN * 128 * 4);  // h  / h2
    float* H1   = (float*)alloc((size_t)NN * 128 * 4);  // h1
    float* DINV = (float*)alloc((size_t)NN * 4);        // deg -> dinv (in place)
    int*   ROW  = (int*)  alloc((size_t)(NN + 1) * 4);
    int*   CUR  = (int*)  alloc((size_t)NN * 4);        // counts, then fill cursor
    int*   CSRS = (int*)  alloc((size_t)NE * 4);
    float* CSRW = (float*)alloc((size_t)NE * 4);
    int*   BLK  = (int*)  alloc(1024);
    float* PART = (float*)alloc((size_t)512 * 256 * 4);
    float* STAT = (float*)alloc(1024);

    int nbScan = (NN + 1023) / 1024;

    hipMemsetAsync(DINV, 0, (size_t)NN * 4, stream);
    hipMemsetAsync(CUR, 0, (size_t)NN * 4, stream);
    deg_count<<<(NE + 255) / 256, 256, 0, stream>>>(ei, ew, DINV, CUR, NE);
    to_dinv<<<(NN + 255) / 256, 256, 0, stream>>>(DINV, NN);
    scan1<<<nbScan, 256, 0, stream>>>(CUR, ROW, BLK, NN);
    scan2<<<1, 256, 0, stream>>>(BLK, nbScan);
    scan3<<<(NN + 255) / 256, 256, 0, stream>>>(ROW, BLK, NN, NE);
    hipMemcpyAsync(CUR, ROW, (size_t)NN * 4, hipMemcpyDeviceToDevice, stream);
    fill_csr<<<(NE + 255) / 256, 256, 0, stream>>>(ei, ew, DINV, CUR, CSRS, CSRW, NE);

    // layer 1
    gemm128<<<512, 256, 0, stream>>>(x, W1, XW, NN);
    aggregate<<<(NN + 3) / 4, 256, 0, stream>>>(XW, ROW, CSRS, CSRW, DINV, b1, H, NN);
    bn_stats<<<512, 256, 0, stream>>>(H, PART, NN);
    bn_final<<<1, 128, 0, stream>>>(PART, gamma, beta, STAT, 512, 1.0f / NN);
    bn_apply<<<2048, 256, 0, stream>>>(H, STAT, H1, NN * 128);

    // layer 2
    gemm128<<<512, 256, 0, stream>>>(H1, W2, XW, NN);
    aggregate<<<(NN + 3) / 4, 256, 0, stream>>>(XW, ROW, CSRS, CSRW, DINV, b2, H, NN);

    // JK max + final projection
    final_proj<<<512, 256, 0, stream>>>(H1, H, Wf, bf, out, NN);
}

// Round 2
// 625.704 us; speedup vs baseline: 1.5536x; 1.5536x over previous
//
#include <hip/hip_runtime.h>

#define NN 100000
#define NE 1600000
#define EPSF 1e-5f

typedef __attribute__((ext_vector_type(8))) short bf16x8;
typedef __attribute__((ext_vector_type(4))) float f32x4;

__device__ __forceinline__ ushort f2b(float f) {
    uint u = __float_as_uint(f);
    uint r = (u + 0x7FFFu + ((u >> 16) & 1u)) >> 16;
    return (ushort)r;
}
__device__ __forceinline__ float b2f(ushort h) { return __uint_as_float(((uint)h) << 16); }

// ---------------- graph preprocessing ----------------

__global__ __launch_bounds__(256) void deg_count(const int* __restrict__ ei, const float* __restrict__ ew,
                                                 float* __restrict__ deg, int* __restrict__ cnt, int E) {
    int e = blockIdx.x * 256 + threadIdx.x;
    if (e < E) {
        int d = ei[E + e];
        atomicAdd(&deg[d], ew[e]);
        atomicAdd(&cnt[d], 1);
    }
}

__global__ __launch_bounds__(256) void to_dinv(float* deg, int n) {
    int i = blockIdx.x * 256 + threadIdx.x;
    if (i < n) deg[i] = rsqrtf(deg[i] + 1.0f);
}

__global__ __launch_bounds__(256) void scan1(const int* __restrict__ cnt, int* __restrict__ out,
                                             int* __restrict__ blk, int n) {
    __shared__ int s[256];
    int t = threadIdx.x;
    int base = blockIdx.x * 1024 + t * 4;
    int v0 = base + 0 < n ? cnt[base + 0] : 0;
    int v1 = base + 1 < n ? cnt[base + 1] : 0;
    int v2 = base + 2 < n ? cnt[base + 2] : 0;
    int v3 = base + 3 < n ? cnt[base + 3] : 0;
    s[t] = v0 + v1 + v2 + v3;
    __syncthreads();
    for (int off = 1; off < 256; off <<= 1) {
        int x = (t >= off) ? s[t - off] : 0;
        __syncthreads();
        s[t] += x;
        __syncthreads();
    }
    int excl = t ? s[t - 1] : 0;
    if (t == 255) blk[blockIdx.x] = s[255];
    if (base + 0 < n) out[base + 0] = excl;
    if (base + 1 < n) out[base + 1] = excl + v0;
    if (base + 2 < n) out[base + 2] = excl + v0 + v1;
    if (base + 3 < n) out[base + 3] = excl + v0 + v1 + v2;
}

__global__ void scan2(int* blk, int nb) {
    __shared__ int s[256];
    int t = threadIdx.x;
    s[t] = t < nb ? blk[t] : 0;
    __syncthreads();
    for (int off = 1; off < 256; off <<= 1) {
        int x = (t >= off) ? s[t - off] : 0;
        __syncthreads();
        s[t] += x;
        __syncthreads();
    }
    if (t < nb) blk[t] = t ? s[t - 1] : 0;
}

__global__ __launch_bounds__(256) void scan3(int* __restrict__ row, const int* __restrict__ blk, int n, int Etot) {
    int i = blockIdx.x * 256 + threadIdx.x;
    if (i < n) row[i] += blk[i >> 10];
    if (i == 0) row[n] = Etot;
}

__global__ __launch_bounds__(256) void fill_csr(const int* __restrict__ ei, const float* __restrict__ ew,
                                                const float* __restrict__ dinv, int* __restrict__ cur,
                                                int* __restrict__ csrs, float* __restrict__ csrw, int E) {
    int e = blockIdx.x * 256 + threadIdx.x;
    if (e < E) {
        int s = ei[e], d = ei[E + e];
        float w = ew[e] * dinv[s] * dinv[d];
        int pos = atomicAdd(&cur[d], 1);
        csrs[pos] = s;
        csrw[pos] = w;
    }
}

// ---------------- weight pre-pack into MFMA B-fragment layout ----------------
// WF[((ks*nc16 + c)*64 + lane)*8 + e] = bf16(W[(ks*32 + (lane>>4)*8 + e)*ncol + c*16 + (lane&15)])

__global__ __launch_bounds__(256) void pack_w(const float* __restrict__ W, ushort* __restrict__ WF, int ncol) {
    int slot = blockIdx.x * 256 + threadIdx.x;
    int nc16 = ncol >> 4;
    int tot = 4 * nc16 * 64;
    if (slot >= tot) return;
    int lane = slot & 63;
    int c = (slot >> 6) % nc16;
    int ks = (slot >> 6) / nc16;
    int col = c * 16 + (lane & 15);
    int k0 = ks * 32 + (lane >> 4) * 8;
#pragma unroll
    for (int e = 0; e < 8; e++) WF[slot * 8 + e] = f2b(W[(k0 + e) * ncol + col]);
}

// ---------------- GEMM via MFMA: C[n,128] = A[n,128] @ W ----------------

template <bool AF32>
__global__ __launch_bounds__(256) void gemm_mfma(const void* __restrict__ Ap, const ushort* __restrict__ WF,
                                                 ushort* __restrict__ C, int ngrp) {
    __shared__ ushort Bl[4 * 8 * 64 * 8];  // 32 KB
    for (int i = threadIdx.x * 8; i < 4 * 8 * 64 * 8; i += 256 * 8)
        *(bf16x8*)&Bl[i] = *(const bf16x8*)&WF[i];
    __syncthreads();
    int wave = __builtin_amdgcn_readfirstlane(threadIdx.x >> 6);
    int lane = threadIdx.x & 63;
    int rg = blockIdx.x * 4 + wave;
    if (rg >= ngrp) return;
    int r0 = rg * 16;
    int rA = r0 + (lane & 15);
    int kb = (lane >> 4) * 8;
    bf16x8 a[4];
    if (AF32) {
        const float* A = (const float*)Ap;
#pragma unroll
        for (int ks = 0; ks < 4; ks++) {
            const float* p = &A[(size_t)rA * 128 + ks * 32 + kb];
            float4 x0 = *(const float4*)p;
            float4 x1 = *(const float4*)(p + 4);
            ushort t[8] = {f2b(x0.x), f2b(x0.y), f2b(x0.z), f2b(x0.w),
                           f2b(x1.x), f2b(x1.y), f2b(x1.z), f2b(x1.w)};
            a[ks] = *(bf16x8*)t;
        }
    } else {
        const ushort* A = (const ushort*)Ap;
#pragma unroll
        for (int ks = 0; ks < 4; ks++)
            a[ks] = *(const bf16x8*)&A[(size_t)rA * 128 + ks * 32 + kb];
    }
#pragma unroll
    for (int c = 0; c < 8; c++) {
        f32x4 acc = {0.f, 0.f, 0.f, 0.f};
#pragma unroll
        for (int ks = 0; ks < 4; ks++) {
            bf16x8 b = *(const bf16x8*)&Bl[((ks * 8 + c) * 64 + lane) * 8];
            acc = __builtin_amdgcn_mfma_f32_16x16x32_bf16(a[ks], b, acc, 0, 0, 0);
        }
        int colb = c * 16 + (lane & 15);
        int rowb = r0 + (lane >> 4) * 4;
#pragma unroll
        for (int r = 0; r < 4; r++)
            C[(size_t)(rowb + r) * 128 + colb] = f2b(acc[r]);
    }
}

// ---------------- final: OUT[n,64] = max(H1,H2) @ Wf + bf (MFMA) ----------------

__global__ __launch_bounds__(256) void final_mfma(const ushort* __restrict__ H1, const ushort* __restrict__ H2,
                                                  const ushort* __restrict__ WF, const float* __restrict__ bfv,
                                                  float* __restrict__ OUT, int ngrp) {
    __shared__ ushort Bl[4 * 4 * 64 * 8];  // 16 KB
    for (int i = threadIdx.x * 8; i < 4 * 4 * 64 * 8; i += 256 * 8)
        *(bf16x8*)&Bl[i] = *(const bf16x8*)&WF[i];
    __syncthreads();
    int wave = __builtin_amdgcn_readfirstlane(threadIdx.x >> 6);
    int lane = threadIdx.x & 63;
    int rg = blockIdx.x * 4 + wave;
    if (rg >= ngrp) return;
    int r0 = rg * 16;
    int rA = r0 + (lane & 15);
    int kb = (lane >> 4) * 8;
    bf16x8 a[4];
#pragma unroll
    for (int ks = 0; ks < 4; ks++) {
        bf16x8 u = *(const bf16x8*)&H1[(size_t)rA * 128 + ks * 32 + kb];
        bf16x8 v = *(const bf16x8*)&H2[(size_t)rA * 128 + ks * 32 + kb];
        ushort t[8];
#pragma unroll
        for (int e = 0; e < 8; e++) {
            ushort ue = (ushort)u[e], ve = (ushort)v[e];
            t[e] = (b2f(ue) >= b2f(ve)) ? ue : ve;  // exact: max of two bf16
        }
        a[ks] = *(bf16x8*)t;
    }
#pragma unroll
    for (int c = 0; c < 4; c++) {
        f32x4 acc = {0.f, 0.f, 0.f, 0.f};
#pragma unroll
        for (int ks = 0; ks < 4; ks++) {
            bf16x8 b = *(const bf16x8*)&Bl[((ks * 4 + c) * 64 + lane) * 8];
            acc = __builtin_amdgcn_mfma_f32_16x16x32_bf16(a[ks], b, acc, 0, 0, 0);
        }
        int colb = c * 16 + (lane & 15);
        int rowb = r0 + (lane >> 4) * 4;
        float bb = bfv[colb];
#pragma unroll
        for (int r = 0; r < 4; r++)
            OUT[(size_t)(rowb + r) * 64 + colb] = acc[r] + bb;
    }
}

// ---------------- aggregation (bf16 features, fp32 accum) ----------------

__global__ __launch_bounds__(256) void aggregate_b(const ushort* __restrict__ XW, const int* __restrict__ row,
                                                   const int* __restrict__ csrs, const float* __restrict__ csrw,
                                                   const float* __restrict__ dinv, const float* __restrict__ bias,
                                                   ushort* __restrict__ OUT, int n) {
    int wave = __builtin_amdgcn_readfirstlane(threadIdx.x >> 6);
    int lane = threadIdx.x & 63;
    int node = blockIdx.x * 4 + wave;
    if (node >= n) return;
    int beg = row[node], end = row[node + 1];
    float ax = 0.f, ay = 0.f;
    int e = beg;
    for (; e + 1 < end; e += 2) {
        int s0 = csrs[e], s1 = csrs[e + 1];
        float w0 = csrw[e], w1 = csrw[e + 1];
        uint v0 = *(const uint*)&XW[(size_t)s0 * 128 + lane * 2];
        uint v1 = *(const uint*)&XW[(size_t)s1 * 128 + lane * 2];
        ax += w0 * __uint_as_float(v0 << 16) + w1 * __uint_as_float(v1 << 16);
        ay += w0 * __uint_as_float(v0 & 0xFFFF0000u) + w1 * __uint_as_float(v1 & 0xFFFF0000u);
    }
    if (e < end) {
        int s0 = csrs[e];
        float w0 = csrw[e];
        uint v0 = *(const uint*)&XW[(size_t)s0 * 128 + lane * 2];
        ax += w0 * __uint_as_float(v0 << 16);
        ay += w0 * __uint_as_float(v0 & 0xFFFF0000u);
    }
    float di = dinv[node], sl = di * di;
    uint vs = *(const uint*)&XW[(size_t)node * 128 + lane * 2];
    float ox = ax + sl * __uint_as_float(vs << 16) + bias[lane * 2];
    float oy = ay + sl * __uint_as_float(vs & 0xFFFF0000u) + bias[lane * 2 + 1];
    uint o = (uint)f2b(ox) | ((uint)f2b(oy) << 16);
    *(uint*)&OUT[(size_t)node * 128 + lane * 2] = o;
}

// ---------------- BatchNorm ----------------

__global__ __launch_bounds__(256) void bn_stats_b(const ushort* __restrict__ H, float* __restrict__ part, int n) {
    int wave = threadIdx.x >> 6;
    int lane = threadIdx.x & 63;
    float2 s = make_float2(0.f, 0.f), q = make_float2(0.f, 0.f);
    for (int r = blockIdx.x * 4 + wave; r < n; r += gridDim.x * 4) {
        uint v = *(const uint*)&H[(size_t)r * 128 + lane * 2];
        float x = __uint_as_float(v << 16);
        float y = __uint_as_float(v & 0xFFFF0000u);
        s.x += x; s.y += y;
        q.x += x * x; q.y += y * y;
    }
    __shared__ float2 reds[4][64];
    __shared__ float2 redq[4][64];
    reds[wave][lane] = s;
    redq[wave][lane] = q;
    __syncthreads();
    if (threadIdx.x < 64) {
        int l = threadIdx.x;
        float2 S = make_float2(0.f, 0.f), Q = make_float2(0.f, 0.f);
#pragma unroll
        for (int w = 0; w < 4; w++) {
            S.x += reds[w][l].x; S.y += reds[w][l].y;
            Q.x += redq[w][l].x; Q.y += redq[w][l].y;
        }
        part[blockIdx.x * 256 + l * 2 + 0] = S.x;
        part[blockIdx.x * 256 + l * 2 + 1] = S.y;
        part[blockIdx.x * 256 + 128 + l * 2 + 0] = Q.x;
        part[blockIdx.x * 256 + 128 + l * 2 + 1] = Q.y;
    }
}

__global__ void bn_final(const float* __restrict__ part, const float* __restrict__ gamma,
                         const float* __restrict__ beta, float* __restrict__ stats, int nb, float invN) {
    int c = threadIdx.x;
    if (c >= 128) return;
    float s = 0.f, q = 0.f;
    for (int b = 0; b < nb; b++) {
        s += part[b * 256 + c];
        q += part[b * 256 + 128 + c];
    }
    float mu = s * invN;
    float var = q * invN - mu * mu;
    float sc = gamma[c] * rsqrtf(var + EPSF);
    stats[c] = sc;
    stats[128 + c] = beta[c] - mu * sc;
}

__global__ __launch_bounds__(256) void bn_apply_b(const ushort* __restrict__ H, const float* __restrict__ stats,
                                                  ushort* __restrict__ H1, int total) {
    __shared__ float s[256];
    s[threadIdx.x] = stats[threadIdx.x];
    __syncthreads();
    int stride = gridDim.x * 256 * 4;
    for (int i = (blockIdx.x * 256 + threadIdx.x) * 4; i < total; i += stride) {
        ushort4 v = *(const ushort4*)&H[i];
        int c = i & 127;
        float f0 = fmaxf(b2f(v.x) * s[c + 0] + s[128 + c + 0], 0.f);
        float f1 = fmaxf(b2f(v.y) * s[c + 1] + s[128 + c + 1], 0.f);
        float f2 = fmaxf(b2f(v.z) * s[c + 2] + s[128 + c + 2], 0.f);
        float f3 = fmaxf(b2f(v.w) * s[c + 3] + s[128 + c + 3], 0.f);
        ushort4 o;
        o.x = f2b(f0); o.y = f2b(f1); o.z = f2b(f2); o.w = f2b(f3);
        *(ushort4*)&H1[i] = o;
    }
}

// ---------------- launch ----------------

extern "C" void kernel_launch(void* const* d_in, const int* in_sizes, int n_in,
                              void* d_out, int out_size, void* d_ws, size_t ws_size,
                              hipStream_t stream) {
    const float* x     = (const float*)d_in[0];
    const int*   ei    = (const int*)  d_in[1];
    const float* ew    = (const float*)d_in[2];
    const float* W1    = (const float*)d_in[3];
    const float* b1    = (const float*)d_in[4];
    const float* gamma = (const float*)d_in[5];
    const float* beta  = (const float*)d_in[6];
    const float* W2    = (const float*)d_in[7];
    const float* b2    = (const float*)d_in[8];
    const float* Wf    = (const float*)d_in[9];
    const float* bf    = (const float*)d_in[10];
    float* out = (float*)d_out;

    char* ws = (char*)d_ws;
    size_t off = 0;
    auto alloc = [&](size_t bytes) {
        void* p = ws + off;
        off += (bytes + 1023) & ~(size_t)1023;
        return p;
    };
    ushort* XWB  = (ushort*)alloc((size_t)NN * 128 * 2);  // xw (layer1) / xw2 (layer2)
    ushort* HB   = (ushort*)alloc((size_t)NN * 128 * 2);  // h (pre-BN) / h2
    ushort* H1B  = (ushort*)alloc((size_t)NN * 128 * 2);  // relu(bn(h))
    ushort* H2B  = (ushort*)alloc((size_t)NN * 128 * 2);  // h2 (post-agg layer2)
    float*  DINV = (float*) alloc((size_t)NN * 4);
    int*    ROW  = (int*)   alloc((size_t)(NN + 1) * 4);
    int*    CUR  = (int*)   alloc((size_t)NN * 4);
    int*    CSRS = (int*)   alloc((size_t)NE * 4);
    float*  CSRW = (float*) alloc((size_t)NE * 4);
    int*    BLK  = (int*)   alloc(1024);
    float*  PART = (float*) alloc((size_t)512 * 256 * 4);
    float*  STAT = (float*) alloc(1024);
    ushort* WF1  = (ushort*)alloc((size_t)4 * 8 * 64 * 8 * 2);
    ushort* WF2  = (ushort*)alloc((size_t)4 * 8 * 64 * 8 * 2);
    ushort* WFF  = (ushort*)alloc((size_t)4 * 4 * 64 * 8 * 2);

    int nbScan = (NN + 1023) / 1024;
    int ngrp = (NN + 15) / 16;          // 6250 (NN divisible by 16)
    int gblocks = (ngrp + 3) / 4;

    hipMemsetAsync(DINV, 0, (size_t)NN * 4, stream);
    hipMemsetAsync(CUR, 0, (size_t)NN * 4, stream);
    deg_count<<<(NE + 255) / 256, 256, 0, stream>>>(ei, ew, DINV, CUR, NE);
    to_dinv<<<(NN + 255) / 256, 256, 0, stream>>>(DINV, NN);
    scan1<<<nbScan, 256, 0, stream>>>(CUR, ROW, BLK, NN);
    scan2<<<1, 256, 0, stream>>>(BLK, nbScan);
    scan3<<<(NN + 255) / 256, 256, 0, stream>>>(ROW, BLK, NN, NE);
    hipMemcpyAsync(CUR, ROW, (size_t)NN * 4, hipMemcpyDeviceToDevice, stream);
    fill_csr<<<(NE + 255) / 256, 256, 0, stream>>>(ei, ew, DINV, CUR, CSRS, CSRW, NE);

    pack_w<<<8, 256, 0, stream>>>(W1, WF1, 128);
    pack_w<<<8, 256, 0, stream>>>(W2, WF2, 128);
    pack_w<<<4, 256, 0, stream>>>(Wf, WFF, 64);

    // layer 1
    gemm_mfma<true><<<gblocks, 256, 0, stream>>>(x, WF1, XWB, ngrp);
    aggregate_b<<<(NN + 3) / 4, 256, 0, stream>>>(XWB, ROW, CSRS, CSRW, DINV, b1, HB, NN);
    bn_stats_b<<<512, 256, 0, stream>>>(HB, PART, NN);
    bn_final<<<1, 128, 0, stream>>>(PART, gamma, beta, STAT, 512, 1.0f / NN);
    bn_apply_b<<<2048, 256, 0, stream>>>(HB, STAT, H1B, NN * 128);

    // layer 2
    gemm_mfma<false><<<gblocks, 256, 0, stream>>>(H1B, WF2, XWB, ngrp);
    aggregate_b<<<(NN + 3) / 4, 256, 0, stream>>>(XWB, ROW, CSRS, CSRW, DINV, b2, H2B, NN);

    // JK max + final projection
    final_mfma<<<gblocks, 256, 0, stream>>>(H1B, H2B, WFF, bf, out, ngrp);
}

// Round 3
// 530.411 us; speedup vs baseline: 1.8327x; 1.1797x over previous
//
#include <hip/hip_runtime.h>

#define NN 100000
#define NE 1600000
#define EPSF 1e-5f

#define NSEG 8
#define SEGSZ 12512            // 8 * 12512 = 100096 >= NN
#define NCHUNK 48
#define CHUNK 33334            // 48 * 33334 >= NE

typedef __attribute__((ext_vector_type(8))) short bf16x8;
typedef __attribute__((ext_vector_type(4))) float f32x4;

__device__ __forceinline__ ushort f2b(float f) {
    uint u = __float_as_uint(f);
    uint r = (u + 0x7FFFu + ((u >> 16) & 1u)) >> 16;
    return (ushort)r;
}
__device__ __forceinline__ float b2f(ushort h) { return __uint_as_float(((uint)h) << 16); }

// ---------------- graph preprocessing (no global atomics) ----------------

// partial histogram: block = (seg, chunk); LDS hist over segment bins
__global__ __launch_bounds__(256) void hist_lds(const int* __restrict__ ei, int* __restrict__ part) {
    __shared__ int h[SEGSZ];
    int seg = blockIdx.x / NCHUNK, chunk = blockIdx.x % NCHUNK;
    for (int i = threadIdx.x; i < SEGSZ; i += 256) h[i] = 0;
    __syncthreads();
    int base = chunk * CHUNK;
    int lim = base + CHUNK; if (lim > NE) lim = NE;
    int segb = seg * SEGSZ;
    for (int e = base + threadIdx.x; e < lim; e += 256) {
        int d = ei[NE + e] - segb;
        if ((unsigned)d < SEGSZ) atomicAdd(&h[d], 1);
    }
    __syncthreads();
    int* p = part + (size_t)blockIdx.x * SEGSZ;
    for (int i = threadIdx.x; i < SEGSZ; i += 256) p[i] = h[i];
}

// exclusive-scan partials along chunk axis; emit per-bin totals
__global__ __launch_bounds__(256) void scan_chunks(int* __restrict__ part, int* __restrict__ cnt) {
    int t = blockIdx.x * 256 + threadIdx.x;
    if (t >= NSEG * SEGSZ) return;
    int seg = t / SEGSZ, b = t % SEGSZ;
    int* p = part + (size_t)seg * NCHUNK * SEGSZ + b;
    int acc = 0;
#pragma unroll 4
    for (int c = 0; c < NCHUNK; c++) {
        int v = p[(size_t)c * SEGSZ];
        p[(size_t)c * SEGSZ] = acc;
        acc += v;
    }
    int gb = seg * SEGSZ + b;
    if (gb < NN) cnt[gb] = acc;
}

// exclusive scan of cnt[0..n) -> out, block partial sums -> blk (blocks of 1024)
__global__ __launch_bounds__(256) void scan1(const int* __restrict__ cnt, int* __restrict__ out,
                                             int* __restrict__ blk, int n) {
    __shared__ int s[256];
    int t = threadIdx.x;
    int base = blockIdx.x * 1024 + t * 4;
    int v0 = base + 0 < n ? cnt[base + 0] : 0;
    int v1 = base + 1 < n ? cnt[base + 1] : 0;
    int v2 = base + 2 < n ? cnt[base + 2] : 0;
    int v3 = base + 3 < n ? cnt[base + 3] : 0;
    s[t] = v0 + v1 + v2 + v3;
    __syncthreads();
    for (int off = 1; off < 256; off <<= 1) {
        int x = (t >= off) ? s[t - off] : 0;
        __syncthreads();
        s[t] += x;
        __syncthreads();
    }
    int excl = t ? s[t - 1] : 0;
    if (t == 255) blk[blockIdx.x] = s[255];
    if (base + 0 < n) out[base + 0] = excl;
    if (base + 1 < n) out[base + 1] = excl + v0;
    if (base + 2 < n) out[base + 2] = excl + v0 + v1;
    if (base + 3 < n) out[base + 3] = excl + v0 + v1 + v2;
}

__global__ void scan2(int* blk, int nb) {
    __shared__ int s[256];
    int t = threadIdx.x;
    s[t] = t < nb ? blk[t] : 0;
    __syncthreads();
    for (int off = 1; off < 256; off <<= 1) {
        int x = (t >= off) ? s[t - off] : 0;
        __syncthreads();
        s[t] += x;
        __syncthreads();
    }
    if (t < nb) blk[t] = t ? s[t - 1] : 0;
}

__global__ __launch_bounds__(256) void scan3(int* __restrict__ row, const int* __restrict__ blk, int n, int Etot) {
    int i = blockIdx.x * 256 + threadIdx.x;
    if (i < n) row[i] += blk[i >> 10];
    if (i == 0) row[n] = Etot;
}

// place edges into CSR (LDS cursors seeded with global offsets; no global atomics)
__global__ __launch_bounds__(256) void place_lds(const int* __restrict__ ei, const float* __restrict__ ew,
                                                 const int* __restrict__ row, const int* __restrict__ part,
                                                 uint2* __restrict__ csr) {
    __shared__ int cur[SEGSZ];
    int seg = blockIdx.x / NCHUNK, chunk = blockIdx.x % NCHUNK;
    int segb = seg * SEGSZ;
    const int* p = part + (size_t)blockIdx.x * SEGSZ;
    for (int i = threadIdx.x; i < SEGSZ; i += 256) {
        int gb = segb + i;
        cur[i] = (gb < NN ? row[gb] : 0) + p[i];
    }
    __syncthreads();
    int base = chunk * CHUNK;
    int lim = base + CHUNK; if (lim > NE) lim = NE;
    for (int e = base + threadIdx.x; e < lim; e += 256) {
        int d = ei[NE + e] - segb;
        if ((unsigned)d < SEGSZ) {
            int pos = atomicAdd(&cur[d], 1);
            csr[pos] = make_uint2((uint)ei[e], __float_as_uint(ew[e]));
        }
    }
}

// deg[d] = sum raw ew over bucket; dinv = rsqrt(deg + 1)
__global__ __launch_bounds__(256) void deg_from_csr(const uint2* __restrict__ csr, const int* __restrict__ row,
                                                    float* __restrict__ dinv, int n) {
    int wave = threadIdx.x >> 6, lane = threadIdx.x & 63;
    int node = blockIdx.x * 4 + wave;
    if (node >= n) return;
    int beg = row[node], end = row[node + 1];
    float s = 0.f;
    for (int e = beg + lane; e < end; e += 64) s += __uint_as_float(csr[e].y);
#pragma unroll
    for (int off = 32; off; off >>= 1) s += __shfl_xor(s, off);
    if (lane == 0) dinv[node] = rsqrtf(s + 1.0f);
}

// csr[e].w = ew * dinv[src] * dinv[dst]
__global__ __launch_bounds__(256) void norm_csr(uint2* __restrict__ csr, const int* __restrict__ row,
                                                const float* __restrict__ dinv, int n) {
    int wave = threadIdx.x >> 6, lane = threadIdx.x & 63;
    int node = blockIdx.x * 4 + wave;
    if (node >= n) return;
    int beg = row[node], end = row[node + 1];
    float di = dinv[node];
    for (int e = beg + lane; e < end; e += 64) {
        uint2 u = csr[e];
        csr[e].y = __float_as_uint(__uint_as_float(u.y) * dinv[u.x] * di);
    }
}

// ---------------- weight pre-pack into MFMA B-fragment layout ----------------

__global__ __launch_bounds__(256) void pack_w(const float* __restrict__ W, ushort* __restrict__ WF, int ncol) {
    int slot = blockIdx.x * 256 + threadIdx.x;
    int nc16 = ncol >> 4;
    int tot = 4 * nc16 * 64;
    if (slot >= tot) return;
    int lane = slot & 63;
    int c = (slot >> 6) % nc16;
    int ks = (slot >> 6) / nc16;
    int col = c * 16 + (lane & 15);
    int k0 = ks * 32 + (lane >> 4) * 8;
#pragma unroll
    for (int e = 0; e < 8; e++) WF[slot * 8 + e] = f2b(W[(k0 + e) * ncol + col]);
}

// ---------------- GEMM via MFMA: C[n,128] = A[n,128] @ W ----------------

template <bool AF32>
__global__ __launch_bounds__(256) void gemm_mfma(const void* __restrict__ Ap, const ushort* __restrict__ WF,
                                                 ushort* __restrict__ C, int ngrp) {
    __shared__ ushort Bl[4 * 8 * 64 * 8];  // 32 KB
    for (int i = threadIdx.x * 8; i < 4 * 8 * 64 * 8; i += 256 * 8)
        *(bf16x8*)&Bl[i] = *(const bf16x8*)&WF[i];
    __syncthreads();
    int wave = __builtin_amdgcn_readfirstlane(threadIdx.x >> 6);
    int lane = threadIdx.x & 63;
    int rg = blockIdx.x * 4 + wave;
    if (rg >= ngrp) return;
    int r0 = rg * 16;
    int rA = r0 + (lane & 15);
    int kb = (lane >> 4) * 8;
    bf16x8 a[4];
    if (AF32) {
        const float* A = (const float*)Ap;
#pragma unroll
        for (int ks = 0; ks < 4; ks++) {
            const float* p = &A[(size_t)rA * 128 + ks * 32 + kb];
            float4 x0 = *(const float4*)p;
            float4 x1 = *(const float4*)(p + 4);
            ushort t[8] = {f2b(x0.x), f2b(x0.y), f2b(x0.z), f2b(x0.w),
                           f2b(x1.x), f2b(x1.y), f2b(x1.z), f2b(x1.w)};
            a[ks] = *(bf16x8*)t;
        }
    } else {
        const ushort* A = (const ushort*)Ap;
#pragma unroll
        for (int ks = 0; ks < 4; ks++)
            a[ks] = *(const bf16x8*)&A[(size_t)rA * 128 + ks * 32 + kb];
    }
#pragma unroll
    for (int c = 0; c < 8; c++) {
        f32x4 acc = {0.f, 0.f, 0.f, 0.f};
#pragma unroll
        for (int ks = 0; ks < 4; ks++) {
            bf16x8 b = *(const bf16x8*)&Bl[((ks * 8 + c) * 64 + lane) * 8];
            acc = __builtin_amdgcn_mfma_f32_16x16x32_bf16(a[ks], b, acc, 0, 0, 0);
        }
        int colb = c * 16 + (lane & 15);
        int rowb = r0 + (lane >> 4) * 4;
#pragma unroll
        for (int r = 0; r < 4; r++)
            C[(size_t)(rowb + r) * 128 + colb] = f2b(acc[r]);
    }
}

// layer-2 GEMM with fused BN-affine + ReLU on A; emits H1 (post-activation) and C = H1 @ W2
__global__ __launch_bounds__(256) void gemm_mfma_bn(const ushort* __restrict__ HB, const float* __restrict__ stats,
                                                    const ushort* __restrict__ WF, ushort* __restrict__ H1,
                                                    ushort* __restrict__ C, int ngrp) {
    __shared__ ushort Bl[4 * 8 * 64 * 8];  // 32 KB
    __shared__ float sst[256];
    sst[threadIdx.x] = stats[threadIdx.x];
    for (int i = threadIdx.x * 8; i < 4 * 8 * 64 * 8; i += 256 * 8)
        *(bf16x8*)&Bl[i] = *(const bf16x8*)&WF[i];
    __syncthreads();
    int wave = __builtin_amdgcn_readfirstlane(threadIdx.x >> 6);
    int lane = threadIdx.x & 63;
    int rg = blockIdx.x * 4 + wave;
    if (rg >= ngrp) return;
    int r0 = rg * 16;
    int rA = r0 + (lane & 15);
    int kb = (lane >> 4) * 8;
    bf16x8 a[4];
#pragma unroll
    for (int ks = 0; ks < 4; ks++) {
        int cbase = ks * 32 + kb;
        bf16x8 u = *(const bf16x8*)&HB[(size_t)rA * 128 + cbase];
        ushort t[8];
#pragma unroll
        for (int e = 0; e < 8; e++) {
            float f = fmaxf(b2f((ushort)u[e]) * sst[cbase + e] + sst[128 + cbase + e], 0.f);
            t[e] = f2b(f);
        }
        a[ks] = *(bf16x8*)t;
        *(bf16x8*)&H1[(size_t)rA * 128 + cbase] = a[ks];
    }
#pragma unroll
    for (int c = 0; c < 8; c++) {
        f32x4 acc = {0.f, 0.f, 0.f, 0.f};
#pragma unroll
        for (int ks = 0; ks < 4; ks++) {
            bf16x8 b = *(const bf16x8*)&Bl[((ks * 8 + c) * 64 + lane) * 8];
            acc = __builtin_amdgcn_mfma_f32_16x16x32_bf16(a[ks], b, acc, 0, 0, 0);
        }
        int colb = c * 16 + (lane & 15);
        int rowb = r0 + (lane >> 4) * 4;
#pragma unroll
        for (int r = 0; r < 4; r++)
            C[(size_t)(rowb + r) * 128 + colb] = f2b(acc[r]);
    }
}

// ---------------- final: OUT[n,64] = max(H1,H2) @ Wf + bf (MFMA) ----------------

__global__ __launch_bounds__(256) void final_mfma(const ushort* __restrict__ H1, const ushort* __restrict__ H2,
                                                  const ushort* __restrict__ WF, const float* __restrict__ bfv,
                                                  float* __restrict__ OUT, int ngrp) {
    __shared__ ushort Bl[4 * 4 * 64 * 8];  // 16 KB
    for (int i = threadIdx.x * 8; i < 4 * 4 * 64 * 8; i += 256 * 8)
        *(bf16x8*)&Bl[i] = *(const bf16x8*)&WF[i];
    __syncthreads();
    int wave = __builtin_amdgcn_readfirstlane(threadIdx.x >> 6);
    int lane = threadIdx.x & 63;
    int rg = blockIdx.x * 4 + wave;
    if (rg >= ngrp) return;
    int r0 = rg * 16;
    int rA = r0 + (lane & 15);
    int kb = (lane >> 4) * 8;
    bf16x8 a[4];
#pragma unroll
    for (int ks = 0; ks < 4; ks++) {
        bf16x8 u = *(const bf16x8*)&H1[(size_t)rA * 128 + ks * 32 + kb];
        bf16x8 v = *(const bf16x8*)&H2[(size_t)rA * 128 + ks * 32 + kb];
        ushort t[8];
#pragma unroll
        for (int e = 0; e < 8; e++) {
            ushort ue = (ushort)u[e], ve = (ushort)v[e];
            t[e] = (b2f(ue) >= b2f(ve)) ? ue : ve;  // exact: max of two bf16
        }
        a[ks] = *(bf16x8*)t;
    }
#pragma unroll
    for (int c = 0; c < 4; c++) {
        f32x4 acc = {0.f, 0.f, 0.f, 0.f};
#pragma unroll
        for (int ks = 0; ks < 4; ks++) {
            bf16x8 b = *(const bf16x8*)&Bl[((ks * 4 + c) * 64 + lane) * 8];
            acc = __builtin_amdgcn_mfma_f32_16x16x32_bf16(a[ks], b, acc, 0, 0, 0);
        }
        int colb = c * 16 + (lane & 15);
        int rowb = r0 + (lane >> 4) * 4;
        float bb = bfv[colb];
#pragma unroll
        for (int r = 0; r < 4; r++)
            OUT[(size_t)(rowb + r) * 64 + colb] = acc[r] + bb;
    }
}

// ---------------- aggregation (bf16 features, fp32 accum, uint2 CSR) ----------------

__global__ __launch_bounds__(256) void aggregate_b2(const ushort* __restrict__ XW, const int* __restrict__ row,
                                                    const uint2* __restrict__ csr, const float* __restrict__ dinv,
                                                    const float* __restrict__ bias, ushort* __restrict__ OUT, int n) {
    int wave = __builtin_amdgcn_readfirstlane(threadIdx.x >> 6);
    int lane = threadIdx.x & 63;
    int node = blockIdx.x * 4 + wave;
    if (node >= n) return;
    int beg = row[node], end = row[node + 1];
    float ax = 0.f, ay = 0.f;
    int e = beg;
    for (; e + 1 < end; e += 2) {
        uint2 p0 = csr[e], p1 = csr[e + 1];
        float w0 = __uint_as_float(p0.y), w1 = __uint_as_float(p1.y);
        uint v0 = *(const uint*)&XW[(size_t)p0.x * 128 + lane * 2];
        uint v1 = *(const uint*)&XW[(size_t)p1.x * 128 + lane * 2];
        ax += w0 * __uint_as_float(v0 << 16) + w1 * __uint_as_float(v1 << 16);
        ay += w0 * __uint_as_float(v0 & 0xFFFF0000u) + w1 * __uint_as_float(v1 & 0xFFFF0000u);
    }
    if (e < end) {
        uint2 p0 = csr[e];
        float w0 = __uint_as_float(p0.y);
        uint v0 = *(const uint*)&XW[(size_t)p0.x * 128 + lane * 2];
        ax += w0 * __uint_as_float(v0 << 16);
        ay += w0 * __uint_as_float(v0 & 0xFFFF0000u);
    }
    float di = dinv[node], sl = di * di;
    uint vs = *(const uint*)&XW[(size_t)node * 128 + lane * 2];
    float ox = ax + sl * __uint_as_float(vs << 16) + bias[lane * 2];
    float oy = ay + sl * __uint_as_float(vs & 0xFFFF0000u) + bias[lane * 2 + 1];
    uint o = (uint)f2b(ox) | ((uint)f2b(oy) << 16);
    *(uint*)&OUT[(size_t)node * 128 + lane * 2] = o;
}

// ---------------- BatchNorm stats ----------------

__global__ __launch_bounds__(256) void bn_stats_b(const ushort* __restrict__ H, float* __restrict__ part, int n) {
    int wave = threadIdx.x >> 6;
    int lane = threadIdx.x & 63;
    float2 s = make_float2(0.f, 0.f), q = make_float2(0.f, 0.f);
    for (int r = blockIdx.x * 4 + wave; r < n; r += gridDim.x * 4) {
        uint v = *(const uint*)&H[(size_t)r * 128 + lane * 2];
        float x = __uint_as_float(v << 16);
        float y = __uint_as_float(v & 0xFFFF0000u);
        s.x += x; s.y += y;
        q.x += x * x; q.y += y * y;
    }
    __shared__ float2 reds[4][64];
    __shared__ float2 redq[4][64];
    reds[wave][lane] = s;
    redq[wave][lane] = q;
    __syncthreads();
    if (threadIdx.x < 64) {
        int l = threadIdx.x;
        float2 S = make_float2(0.f, 0.f), Q = make_float2(0.f, 0.f);
#pragma unroll
        for (int w = 0; w < 4; w++) {
            S.x += reds[w][l].x; S.y += reds[w][l].y;
            Q.x += redq[w][l].x; Q.y += redq[w][l].y;
        }
        part[blockIdx.x * 256 + l * 2 + 0] = S.x;
        part[blockIdx.x * 256 + l * 2 + 1] = S.y;
        part[blockIdx.x * 256 + 128 + l * 2 + 0] = Q.x;
        part[blockIdx.x * 256 + 128 + l * 2 + 1] = Q.y;
    }
}

__global__ void bn_final(const float* __restrict__ part, const float* __restrict__ gamma,
                         const float* __restrict__ beta, float* __restrict__ stats, int nb, float invN) {
    int c = threadIdx.x;
    if (c >= 128) return;
    float s = 0.f, q = 0.f;
    for (int b = 0; b < nb; b++) {
        s += part[b * 256 + c];
        q += part[b * 256 + 128 + c];
    }
    float mu = s * invN;
    float var = q * invN - mu * mu;
    float sc = gamma[c] * rsqrtf(var + EPSF);
    stats[c] = sc;
    stats[128 + c] = beta[c] - mu * sc;
}

// ---------------- launch ----------------

extern "C" void kernel_launch(void* const* d_in, const int* in_sizes, int n_in,
                              void* d_out, int out_size, void* d_ws, size_t ws_size,
                              hipStream_t stream) {
    const float* x     = (const float*)d_in[0];
    const int*   ei    = (const int*)  d_in[1];
    const float* ew    = (const float*)d_in[2];
    const float* W1    = (const float*)d_in[3];
    const float* b1    = (const float*)d_in[4];
    const float* gamma = (const float*)d_in[5];
    const float* beta  = (const float*)d_in[6];
    const float* W2    = (const float*)d_in[7];
    const float* b2    = (const float*)d_in[8];
    const float* Wf    = (const float*)d_in[9];
    const float* bf    = (const float*)d_in[10];
    float* out = (float*)d_out;

    char* ws = (char*)d_ws;
    size_t off = 0;
    auto alloc = [&](size_t bytes) {
        void* p = ws + off;
        off += (bytes + 1023) & ~(size_t)1023;
        return p;
    };
    // XWB region doubles as PART (histogram partials) during preprocessing:
    // PART bytes = NSEG*NCHUNK*SEGSZ*4 = 8*48*12512*4 = 19.2 MB < 25.6 MB
    ushort* XWB  = (ushort*)alloc((size_t)NN * 128 * 2);  // xw / xw2 ; aliased as PART pre-GEMM
    ushort* HB   = (ushort*)alloc((size_t)NN * 128 * 2);  // h (pre-BN)
    ushort* H1B  = (ushort*)alloc((size_t)NN * 128 * 2);  // relu(bn(h))
    ushort* H2B  = (ushort*)alloc((size_t)NN * 128 * 2);  // h2
    float*  DINV = (float*) alloc((size_t)NN * 4);
    int*    ROW  = (int*)   alloc((size_t)(NN + 1) * 4);
    int*    CNT  = (int*)   alloc((size_t)NN * 4);
    uint2*  CSR8 = (uint2*) alloc((size_t)NE * 8);
    int*    BLK  = (int*)   alloc(1024);
    float*  PARTBN = (float*)alloc((size_t)512 * 256 * 4);
    float*  STAT = (float*) alloc(1024);
    ushort* WF1  = (ushort*)alloc((size_t)4 * 8 * 64 * 8 * 2);
    ushort* WF2  = (ushort*)alloc((size_t)4 * 8 * 64 * 8 * 2);
    ushort* WFF  = (ushort*)alloc((size_t)4 * 4 * 64 * 8 * 2);
    int* PART = (int*)XWB;

    int nbScan = (NN + 1023) / 1024;                 // 98
    int ngrp = NN / 16;                              // 6250
    int gblocks = (ngrp + 3) / 4;                    // 1563

    // ---- preprocessing: counting-sort edges by dst, zero global atomics ----
    hist_lds<<<NSEG * NCHUNK, 256, 0, stream>>>(ei, PART);
    scan_chunks<<<(NSEG * SEGSZ) / 256, 256, 0, stream>>>(PART, CNT);
    scan1<<<nbScan, 256, 0, stream>>>(CNT, ROW, BLK, NN);
    scan2<<<1, 256, 0, stream>>>(BLK, nbScan);
    scan3<<<(NN + 255) / 256, 256, 0, stream>>>(ROW, BLK, NN, NE);
    place_lds<<<NSEG * NCHUNK, 256, 0, stream>>>(ei, ew, ROW, PART, CSR8);
    deg_from_csr<<<(NN + 3) / 4, 256, 0, stream>>>(CSR8, ROW, DINV, NN);
    norm_csr<<<(NN + 3) / 4, 256, 0, stream>>>(CSR8, ROW, DINV, NN);

    pack_w<<<8, 256, 0, stream>>>(W1, WF1, 128);
    pack_w<<<8, 256, 0, stream>>>(W2, WF2, 128);
    pack_w<<<4, 256, 0, stream>>>(Wf, WFF, 64);

    // layer 1
    gemm_mfma<true><<<gblocks, 256, 0, stream>>>(x, WF1, XWB, ngrp);
    aggregate_b2<<<(NN + 3) / 4, 256, 0, stream>>>(XWB, ROW, CSR8, DINV, b1, HB, NN);
    bn_stats_b<<<512, 256, 0, stream>>>(HB, PARTBN, NN);
    bn_final<<<1, 128, 0, stream>>>(PARTBN, gamma, beta, STAT, 512, 1.0f / NN);

    // layer 2 (BN-affine + ReLU fused into A-load; emits H1B and XWB = H1 @ W2)
    gemm_mfma_bn<<<gblocks, 256, 0, stream>>>(HB, STAT, WF2, H1B, XWB, ngrp);
    aggregate_b2<<<(NN + 3) / 4, 256, 0, stream>>>(XWB, ROW, CSR8, DINV, b2, H2B, NN);

    // JK max + final projection
    final_mfma<<<gblocks, 256, 0, stream>>>(H1B, H2B, WFF, bf, out, ngrp);
}

// Round 4
// 406.480 us; speedup vs baseline: 2.3914x; 1.3049x over previous
//
#include <hip/hip_runtime.h>

#define NN 100000
#define NE 1600000
#define EPSF 1e-5f

#define NB 1563        // node buckets of 64: (NN+63)/64
#define NCHUNK 256
#define CHUNK 6250     // NCHUNK * CHUNK == NE
#define CAP 2048       // per-bucket LDS edge staging (mean 1024, sigma 32)

typedef __attribute__((ext_vector_type(8))) short bf16x8;
typedef __attribute__((ext_vector_type(4))) float f32x4;

__device__ __forceinline__ ushort f2b(float f) {
    uint u = __float_as_uint(f);
    uint r = (u + 0x7FFFu + ((u >> 16) & 1u)) >> 16;
    return (ushort)r;
}
__device__ __forceinline__ float b2f(ushort h) { return __uint_as_float(((uint)h) << 16); }

// ---------------- preprocessing: two-level counting sort by dst ----------------

// level-1 histogram over 64-node buckets; one pass over dst
__global__ __launch_bounds__(256) void hist_b(const int* __restrict__ ei, int* __restrict__ part) {
    __shared__ int h[NB];
    int chunk = blockIdx.x;
    for (int i = threadIdx.x; i < NB; i += 256) h[i] = 0;
    __syncthreads();
    int base = chunk * CHUNK;
    int lim = base + CHUNK; if (lim > NE) lim = NE;
    for (int e = base + threadIdx.x; e < lim; e += 256)
        atomicAdd(&h[ei[NE + e] >> 6], 1);
    __syncthreads();
    int* p = part + (size_t)chunk * NB;
    for (int i = threadIdx.x; i < NB; i += 256) p[i] = h[i];
}

// exclusive-scan partials along chunk axis; emit per-bucket totals
__global__ __launch_bounds__(256) void scan_chunks_b(int* __restrict__ part, int* __restrict__ cnt) {
    int b = blockIdx.x * 256 + threadIdx.x;
    if (b >= NB) return;
    int acc = 0;
    for (int c = 0; c < NCHUNK; c++) {
        int v = part[(size_t)c * NB + b];
        part[(size_t)c * NB + b] = acc;
        acc += v;
    }
    cnt[b] = acc;
}

// exclusive scan of 1563 bucket counts (single block)
__global__ __launch_bounds__(256) void bucket_scan(const int* __restrict__ cnt, int* __restrict__ bstart) {
    __shared__ int s[256];
    int t = threadIdx.x;
    int loc[7];
    int sum = 0;
#pragma unroll
    for (int j = 0; j < 7; j++) {
        int i = t * 7 + j;
        int v = (i < NB) ? cnt[i] : 0;
        loc[j] = sum;
        sum += v;
    }
    s[t] = sum;
    __syncthreads();
    for (int off = 1; off < 256; off <<= 1) {
        int x = (t >= off) ? s[t - off] : 0;
        __syncthreads();
        s[t] += x;
        __syncthreads();
    }
    int base = t ? s[t - 1] : 0;
#pragma unroll
    for (int j = 0; j < 7; j++) {
        int i = t * 7 + j;
        if (i < NB) bstart[i] = base + loc[j];
    }
    if (t == 0) bstart[NB] = NE;
}

// place edges to bucket granularity; payload = {src | dl<<17, raw ew}
__global__ __launch_bounds__(256) void place_b(const int* __restrict__ ei, const float* __restrict__ ew,
                                               const int* __restrict__ bstart, const int* __restrict__ part,
                                               uint2* __restrict__ csr) {
    __shared__ int cur[NB];
    int chunk = blockIdx.x;
    const int* p = part + (size_t)chunk * NB;
    for (int i = threadIdx.x; i < NB; i += 256) cur[i] = bstart[i] + p[i];
    __syncthreads();
    int base = chunk * CHUNK;
    int lim = base + CHUNK; if (lim > NE) lim = NE;
    for (int e = base + threadIdx.x; e < lim; e += 256) {
        int s = ei[e], d = ei[NE + e];
        float w = ew[e];
        int pos = atomicAdd(&cur[d >> 6], 1);
        csr[pos] = make_uint2((uint)s | ((uint)(d & 63) << 17), __float_as_uint(w));
    }
}

// per-bucket LDS counting sort -> per-node CSR; fused degree -> dinv, row pointers
__global__ __launch_bounds__(256) void subsort(uint2* __restrict__ csr, const int* __restrict__ bstart,
                                               int* __restrict__ row, float* __restrict__ dinv) {
    __shared__ uint2 E[CAP];
    __shared__ int cnt[64];
    __shared__ int cur[64];
    __shared__ float degf[64];
    int bkt = blockIdx.x;
    int beg = bstart[bkt], end = bstart[bkt + 1];
    int m = end - beg;
    if (threadIdx.x < 64) { cnt[threadIdx.x] = 0; degf[threadIdx.x] = 0.f; }
    __syncthreads();
    for (int i = threadIdx.x; i < m; i += 256) {
        uint2 ed = csr[beg + i];
        if (i < CAP) E[i] = ed;
        int dl = (ed.x >> 17) & 63;
        atomicAdd(&cnt[dl], 1);
        atomicAdd(&degf[dl], __uint_as_float(ed.y));
    }
    __syncthreads();
    if (threadIdx.x < 64) {
        int p = 0;
        for (int j = 0; j < (int)threadIdx.x; j++) p += cnt[j];
        cur[threadIdx.x] = p;
        int node = bkt * 64 + threadIdx.x;
        if (node < NN) {
            row[node] = beg + p;
            dinv[node] = rsqrtf(degf[threadIdx.x] + 1.0f);
        }
        if (bkt == NB - 1 && threadIdx.x == 0) row[NN] = NE;
    }
    __syncthreads();
    for (int i = threadIdx.x; i < m; i += 256) {
        uint2 ed = E[i < CAP ? i : 0];
        int dl = (ed.x >> 17) & 63;
        int pos = atomicAdd(&cur[dl], 1);
        csr[beg + pos] = make_uint2(ed.x & 0x1FFFFu, ed.y);
    }
}

// csr[e].y = ew * dinv[src] * dinv[dst]
__global__ __launch_bounds__(256) void norm_csr(uint2* __restrict__ csr, const int* __restrict__ row,
                                                const float* __restrict__ dinv, int n) {
    int wave = threadIdx.x >> 6, lane = threadIdx.x & 63;
    int node = blockIdx.x * 4 + wave;
    if (node >= n) return;
    int beg = row[node], end = row[node + 1];
    float di = dinv[node];
    for (int e = beg + lane; e < end; e += 64) {
        uint2 u = csr[e];
        csr[e].y = __float_as_uint(__uint_as_float(u.y) * dinv[u.x] * di);
    }
}

// ---------------- weight pre-pack into MFMA B-fragment layout ----------------

__global__ __launch_bounds__(256) void pack_w(const float* __restrict__ W, ushort* __restrict__ WF, int ncol) {
    int slot = blockIdx.x * 256 + threadIdx.x;
    int nc16 = ncol >> 4;
    int tot = 4 * nc16 * 64;
    if (slot >= tot) return;
    int lane = slot & 63;
    int c = (slot >> 6) % nc16;
    int ks = (slot >> 6) / nc16;
    int col = c * 16 + (lane & 15);
    int k0 = ks * 32 + (lane >> 4) * 8;
#pragma unroll
    for (int e = 0; e < 8; e++) WF[slot * 8 + e] = f2b(W[(k0 + e) * ncol + col]);
}

// ---------------- GEMM via MFMA: C[n,128] = A[n,128] @ W ----------------

template <bool AF32>
__global__ __launch_bounds__(256) void gemm_mfma(const void* __restrict__ Ap, const ushort* __restrict__ WF,
                                                 ushort* __restrict__ C, int ngrp) {
    __shared__ ushort Bl[4 * 8 * 64 * 8];  // 32 KB
    for (int i = threadIdx.x * 8; i < 4 * 8 * 64 * 8; i += 256 * 8)
        *(bf16x8*)&Bl[i] = *(const bf16x8*)&WF[i];
    __syncthreads();
    int wave = __builtin_amdgcn_readfirstlane(threadIdx.x >> 6);
    int lane = threadIdx.x & 63;
    int rg = blockIdx.x * 4 + wave;
    if (rg >= ngrp) return;
    int r0 = rg * 16;
    int rA = r0 + (lane & 15);
    int kb = (lane >> 4) * 8;
    bf16x8 a[4];
    if (AF32) {
        const float* A = (const float*)Ap;
#pragma unroll
        for (int ks = 0; ks < 4; ks++) {
            const float* p = &A[(size_t)rA * 128 + ks * 32 + kb];
            float4 x0 = *(const float4*)p;
            float4 x1 = *(const float4*)(p + 4);
            ushort t[8] = {f2b(x0.x), f2b(x0.y), f2b(x0.z), f2b(x0.w),
                           f2b(x1.x), f2b(x1.y), f2b(x1.z), f2b(x1.w)};
            a[ks] = *(bf16x8*)t;
        }
    } else {
        const ushort* A = (const ushort*)Ap;
#pragma unroll
        for (int ks = 0; ks < 4; ks++)
            a[ks] = *(const bf16x8*)&A[(size_t)rA * 128 + ks * 32 + kb];
    }
#pragma unroll
    for (int c = 0; c < 8; c++) {
        f32x4 acc = {0.f, 0.f, 0.f, 0.f};
#pragma unroll
        for (int ks = 0; ks < 4; ks++) {
            bf16x8 b = *(const bf16x8*)&Bl[((ks * 8 + c) * 64 + lane) * 8];
            acc = __builtin_amdgcn_mfma_f32_16x16x32_bf16(a[ks], b, acc, 0, 0, 0);
        }
        int colb = c * 16 + (lane & 15);
        int rowb = r0 + (lane >> 4) * 4;
#pragma unroll
        for (int r = 0; r < 4; r++)
            C[(size_t)(rowb + r) * 128 + colb] = f2b(acc[r]);
    }
}

// layer-2 GEMM with fused BN-affine + ReLU on A; emits H1 and C = H1 @ W2
__global__ __launch_bounds__(256) void gemm_mfma_bn(const ushort* __restrict__ HB, const float* __restrict__ stats,
                                                    const ushort* __restrict__ WF, ushort* __restrict__ H1,
                                                    ushort* __restrict__ C, int ngrp) {
    __shared__ ushort Bl[4 * 8 * 64 * 8];  // 32 KB
    __shared__ float sst[256];
    sst[threadIdx.x] = stats[threadIdx.x];
    for (int i = threadIdx.x * 8; i < 4 * 8 * 64 * 8; i += 256 * 8)
        *(bf16x8*)&Bl[i] = *(const bf16x8*)&WF[i];
    __syncthreads();
    int wave = __builtin_amdgcn_readfirstlane(threadIdx.x >> 6);
    int lane = threadIdx.x & 63;
    int rg = blockIdx.x * 4 + wave;
    if (rg >= ngrp) return;
    int r0 = rg * 16;
    int rA = r0 + (lane & 15);
    int kb = (lane >> 4) * 8;
    bf16x8 a[4];
#pragma unroll
    for (int ks = 0; ks < 4; ks++) {
        int cbase = ks * 32 + kb;
        bf16x8 u = *(const bf16x8*)&HB[(size_t)rA * 128 + cbase];
        ushort t[8];
#pragma unroll
        for (int e = 0; e < 8; e++) {
            float f = fmaxf(b2f((ushort)u[e]) * sst[cbase + e] + sst[128 + cbase + e], 0.f);
            t[e] = f2b(f);
        }
        a[ks] = *(bf16x8*)t;
        *(bf16x8*)&H1[(size_t)rA * 128 + cbase] = a[ks];
    }
#pragma unroll
    for (int c = 0; c < 8; c++) {
        f32x4 acc = {0.f, 0.f, 0.f, 0.f};
#pragma unroll
        for (int ks = 0; ks < 4; ks++) {
            bf16x8 b = *(const bf16x8*)&Bl[((ks * 8 + c) * 64 + lane) * 8];
            acc = __builtin_amdgcn_mfma_f32_16x16x32_bf16(a[ks], b, acc, 0, 0, 0);
        }
        int colb = c * 16 + (lane & 15);
        int rowb = r0 + (lane >> 4) * 4;
#pragma unroll
        for (int r = 0; r < 4; r++)
            C[(size_t)(rowb + r) * 128 + colb] = f2b(acc[r]);
    }
}

// ---------------- final: OUT[n,64] = max(H1,H2) @ Wf + bf (MFMA) ----------------

__global__ __launch_bounds__(256) void final_mfma(const ushort* __restrict__ H1, const ushort* __restrict__ H2,
                                                  const ushort* __restrict__ WF, const float* __restrict__ bfv,
                                                  float* __restrict__ OUT, int ngrp) {
    __shared__ ushort Bl[4 * 4 * 64 * 8];  // 16 KB
    for (int i = threadIdx.x * 8; i < 4 * 4 * 64 * 8; i += 256 * 8)
        *(bf16x8*)&Bl[i] = *(const bf16x8*)&WF[i];
    __syncthreads();
    int wave = __builtin_amdgcn_readfirstlane(threadIdx.x >> 6);
    int lane = threadIdx.x & 63;
    int rg = blockIdx.x * 4 + wave;
    if (rg >= ngrp) return;
    int r0 = rg * 16;
    int rA = r0 + (lane & 15);
    int kb = (lane >> 4) * 8;
    bf16x8 a[4];
#pragma unroll
    for (int ks = 0; ks < 4; ks++) {
        bf16x8 u = *(const bf16x8*)&H1[(size_t)rA * 128 + ks * 32 + kb];
        bf16x8 v = *(const bf16x8*)&H2[(size_t)rA * 128 + ks * 32 + kb];
        ushort t[8];
#pragma unroll
        for (int e = 0; e < 8; e++) {
            ushort ue = (ushort)u[e], ve = (ushort)v[e];
            t[e] = (b2f(ue) >= b2f(ve)) ? ue : ve;
        }
        a[ks] = *(bf16x8*)t;
    }
#pragma unroll
    for (int c = 0; c < 4; c++) {
        f32x4 acc = {0.f, 0.f, 0.f, 0.f};
#pragma unroll
        for (int ks = 0; ks < 4; ks++) {
            bf16x8 b = *(const bf16x8*)&Bl[((ks * 4 + c) * 64 + lane) * 8];
            acc = __builtin_amdgcn_mfma_f32_16x16x32_bf16(a[ks], b, acc, 0, 0, 0);
        }
        int colb = c * 16 + (lane & 15);
        int rowb = r0 + (lane >> 4) * 4;
        float bb = bfv[colb];
#pragma unroll
        for (int r = 0; r < 4; r++)
            OUT[(size_t)(rowb + r) * 64 + colb] = acc[r] + bb;
    }
}

// ---------------- aggregation (bf16 features, fp32 accum, unroll-4) ----------------

__global__ __launch_bounds__(256) void aggregate_b2(const ushort* __restrict__ XW, const int* __restrict__ row,
                                                    const uint2* __restrict__ csr, const float* __restrict__ dinv,
                                                    const float* __restrict__ bias, ushort* __restrict__ OUT, int n) {
    int wave = __builtin_amdgcn_readfirstlane(threadIdx.x >> 6);
    int lane = threadIdx.x & 63;
    int node = blockIdx.x * 4 + wave;
    if (node >= n) return;
    int beg = row[node], end = row[node + 1];
    float ax = 0.f, ay = 0.f;
    int e = beg;
    for (; e + 3 < end; e += 4) {
        uint2 p0 = csr[e], p1 = csr[e + 1], p2 = csr[e + 2], p3 = csr[e + 3];
        uint v0 = *(const uint*)&XW[(size_t)p0.x * 128 + lane * 2];
        uint v1 = *(const uint*)&XW[(size_t)p1.x * 128 + lane * 2];
        uint v2 = *(const uint*)&XW[(size_t)p2.x * 128 + lane * 2];
        uint v3 = *(const uint*)&XW[(size_t)p3.x * 128 + lane * 2];
        float w0 = __uint_as_float(p0.y), w1 = __uint_as_float(p1.y);
        float w2 = __uint_as_float(p2.y), w3 = __uint_as_float(p3.y);
        ax += w0 * __uint_as_float(v0 << 16) + w1 * __uint_as_float(v1 << 16) +
              w2 * __uint_as_float(v2 << 16) + w3 * __uint_as_float(v3 << 16);
        ay += w0 * __uint_as_float(v0 & 0xFFFF0000u) + w1 * __uint_as_float(v1 & 0xFFFF0000u) +
              w2 * __uint_as_float(v2 & 0xFFFF0000u) + w3 * __uint_as_float(v3 & 0xFFFF0000u);
    }
    for (; e < end; e++) {
        uint2 p0 = csr[e];
        float w0 = __uint_as_float(p0.y);
        uint v0 = *(const uint*)&XW[(size_t)p0.x * 128 + lane * 2];
        ax += w0 * __uint_as_float(v0 << 16);
        ay += w0 * __uint_as_float(v0 & 0xFFFF0000u);
    }
    float di = dinv[node], sl = di * di;
    uint vs = *(const uint*)&XW[(size_t)node * 128 + lane * 2];
    float ox = ax + sl * __uint_as_float(vs << 16) + bias[lane * 2];
    float oy = ay + sl * __uint_as_float(vs & 0xFFFF0000u) + bias[lane * 2 + 1];
    uint o = (uint)f2b(ox) | ((uint)f2b(oy) << 16);
    *(uint*)&OUT[(size_t)node * 128 + lane * 2] = o;
}

// ---------------- BatchNorm stats ----------------

__global__ __launch_bounds__(256) void bn_stats_b(const ushort* __restrict__ H, float* __restrict__ part, int n) {
    int wave = threadIdx.x >> 6;
    int lane = threadIdx.x & 63;
    float2 s = make_float2(0.f, 0.f), q = make_float2(0.f, 0.f);
    for (int r = blockIdx.x * 4 + wave; r < n; r += gridDim.x * 4) {
        uint v = *(const uint*)&H[(size_t)r * 128 + lane * 2];
        float x = __uint_as_float(v << 16);
        float y = __uint_as_float(v & 0xFFFF0000u);
        s.x += x; s.y += y;
        q.x += x * x; q.y += y * y;
    }
    __shared__ float2 reds[4][64];
    __shared__ float2 redq[4][64];
    reds[wave][lane] = s;
    redq[wave][lane] = q;
    __syncthreads();
    if (threadIdx.x < 64) {
        int l = threadIdx.x;
        float2 S = make_float2(0.f, 0.f), Q = make_float2(0.f, 0.f);
#pragma unroll
        for (int w = 0; w < 4; w++) {
            S.x += reds[w][l].x; S.y += reds[w][l].y;
            Q.x += redq[w][l].x; Q.y += redq[w][l].y;
        }
        part[blockIdx.x * 256 + l * 2 + 0] = S.x;
        part[blockIdx.x * 256 + l * 2 + 1] = S.y;
        part[blockIdx.x * 256 + 128 + l * 2 + 0] = Q.x;
        part[blockIdx.x * 256 + 128 + l * 2 + 1] = Q.y;
    }
}

__global__ void bn_final(const float* __restrict__ part, const float* __restrict__ gamma,
                         const float* __restrict__ beta, float* __restrict__ stats, int nb, float invN) {
    int c = threadIdx.x;
    if (c >= 128) return;
    float s = 0.f, q = 0.f;
    for (int b = 0; b < nb; b++) {
        s += part[b * 256 + c];
        q += part[b * 256 + 128 + c];
    }
    float mu = s * invN;
    float var = q * invN - mu * mu;
    float sc = gamma[c] * rsqrtf(var + EPSF);
    stats[c] = sc;
    stats[128 + c] = beta[c] - mu * sc;
}

// ---------------- launch ----------------

extern "C" void kernel_launch(void* const* d_in, const int* in_sizes, int n_in,
                              void* d_out, int out_size, void* d_ws, size_t ws_size,
                              hipStream_t stream) {
    const float* x     = (const float*)d_in[0];
    const int*   ei    = (const int*)  d_in[1];
    const float* ew    = (const float*)d_in[2];
    const float* W1    = (const float*)d_in[3];
    const float* b1    = (const float*)d_in[4];
    const float* gamma = (const float*)d_in[5];
    const float* beta  = (const float*)d_in[6];
    const float* W2    = (const float*)d_in[7];
    const float* b2    = (const float*)d_in[8];
    const float* Wf    = (const float*)d_in[9];
    const float* bf    = (const float*)d_in[10];
    float* out = (float*)d_out;

    char* ws = (char*)d_ws;
    size_t off = 0;
    auto alloc = [&](size_t bytes) {
        void* p = ws + off;
        off += (bytes + 1023) & ~(size_t)1023;
        return p;
    };
    // PART (NCHUNK*NB*4 = 1.6 MB) aliases XWB (25.6 MB) — used only pre-GEMM
    ushort* XWB  = (ushort*)alloc((size_t)NN * 128 * 2);
    ushort* HB   = (ushort*)alloc((size_t)NN * 128 * 2);
    ushort* H1B  = (ushort*)alloc((size_t)NN * 128 * 2);
    ushort* H2B  = (ushort*)alloc((size_t)NN * 128 * 2);
    float*  DINV = (float*) alloc((size_t)NN * 4);
    int*    ROW  = (int*)   alloc((size_t)(NN + 1) * 4);
    int*    CNT  = (int*)   alloc((size_t)NB * 4);
    int*    BSTART = (int*) alloc((size_t)(NB + 1) * 4);
    uint2*  CSR8 = (uint2*) alloc((size_t)NE * 8);
    float*  PARTBN = (float*)alloc((size_t)512 * 256 * 4);
    float*  STAT = (float*) alloc(1024);
    ushort* WF1  = (ushort*)alloc((size_t)4 * 8 * 64 * 8 * 2);
    ushort* WF2  = (ushort*)alloc((size_t)4 * 8 * 64 * 8 * 2);
    ushort* WFF  = (ushort*)alloc((size_t)4 * 4 * 64 * 8 * 2);
    int* PART = (int*)XWB;

    int ngrp = NN / 16;               // 6250
    int gblocks = (ngrp + 3) / 4;     // 1563

    // ---- two-level counting sort (bucket=node>>6), zero global atomics ----
    hist_b<<<NCHUNK, 256, 0, stream>>>(ei, PART);
    scan_chunks_b<<<(NB + 255) / 256, 256, 0, stream>>>(PART, CNT);
    bucket_scan<<<1, 256, 0, stream>>>(CNT, BSTART);
    place_b<<<NCHUNK, 256, 0, stream>>>(ei, ew, BSTART, PART, CSR8);
    subsort<<<NB, 256, 0, stream>>>(CSR8, BSTART, ROW, DINV);
    norm_csr<<<(NN + 3) / 4, 256, 0, stream>>>(CSR8, ROW, DINV, NN);

    pack_w<<<8, 256, 0, stream>>>(W1, WF1, 128);
    pack_w<<<8, 256, 0, stream>>>(W2, WF2, 128);
    pack_w<<<4, 256, 0, stream>>>(Wf, WFF, 64);

    // layer 1
    gemm_mfma<true><<<gblocks, 256, 0, stream>>>(x, WF1, XWB, ngrp);
    aggregate_b2<<<(NN + 3) / 4, 256, 0, stream>>>(XWB, ROW, CSR8, DINV, b1, HB, NN);
    bn_stats_b<<<512, 256, 0, stream>>>(HB, PARTBN, NN);
    bn_final<<<1, 128, 0, stream>>>(PARTBN, gamma, beta, STAT, 512, 1.0f / NN);

    // layer 2 (BN+ReLU fused into A-load; emits H1B and XWB = H1 @ W2)
    gemm_mfma_bn<<<gblocks, 256, 0, stream>>>(HB, STAT, WF2, H1B, XWB, ngrp);
    aggregate_b2<<<(NN + 3) / 4, 256, 0, stream>>>(XWB, ROW, CSR8, DINV, b2, H2B, NN);

    // JK max + final projection
    final_mfma<<<gblocks, 256, 0, stream>>>(H1B, H2B, WFF, bf, out, ngrp);
}

// Round 5
// 288.855 us; speedup vs baseline: 3.3653x; 1.4072x over previous
//
#include <hip/hip_runtime.h>

#define NN 100000
#define NE 1600000
#define EPSF 1e-5f

#define NB 1563        // node buckets of 64: (NN+63)/64
#define NCHUNK 256
#define CHUNK 6250     // NCHUNK * CHUNK == NE
#define CAP 2048       // per-bucket LDS edge staging (mean 1024, sigma 32)

typedef __attribute__((ext_vector_type(8))) short bf16x8;
typedef __attribute__((ext_vector_type(4))) float f32x4;

__device__ __forceinline__ ushort f2b(float f) {
    uint u = __float_as_uint(f);
    uint r = (u + 0x7FFFu + ((u >> 16) & 1u)) >> 16;
    return (ushort)r;
}
__device__ __forceinline__ float b2f(ushort h) { return __uint_as_float(((uint)h) << 16); }

// ---------------- preprocessing: two-level counting sort by dst ----------------

__global__ __launch_bounds__(256) void hist_b(const int* __restrict__ ei, int* __restrict__ part) {
    __shared__ int h[NB];
    int chunk = blockIdx.x;
    for (int i = threadIdx.x; i < NB; i += 256) h[i] = 0;
    __syncthreads();
    int base = chunk * CHUNK;
    int lim = base + CHUNK; if (lim > NE) lim = NE;
    for (int e = base + threadIdx.x; e < lim; e += 256)
        atomicAdd(&h[ei[NE + e] >> 6], 1);
    __syncthreads();
    int* p = part + (size_t)chunk * NB;
    for (int i = threadIdx.x; i < NB; i += 256) p[i] = h[i];
}

__global__ __launch_bounds__(256) void scan_chunks_b(int* __restrict__ part, int* __restrict__ cnt) {
    int b = blockIdx.x * 256 + threadIdx.x;
    if (b >= NB) return;
    int acc = 0;
    for (int c = 0; c < NCHUNK; c++) {
        int v = part[(size_t)c * NB + b];
        part[(size_t)c * NB + b] = acc;
        acc += v;
    }
    cnt[b] = acc;
}

__global__ __launch_bounds__(256) void bucket_scan(const int* __restrict__ cnt, int* __restrict__ bstart) {
    __shared__ int s[256];
    int t = threadIdx.x;
    int loc[7];
    int sum = 0;
#pragma unroll
    for (int j = 0; j < 7; j++) {
        int i = t * 7 + j;
        int v = (i < NB) ? cnt[i] : 0;
        loc[j] = sum;
        sum += v;
    }
    s[t] = sum;
    __syncthreads();
    for (int off = 1; off < 256; off <<= 1) {
        int x = (t >= off) ? s[t - off] : 0;
        __syncthreads();
        s[t] += x;
        __syncthreads();
    }
    int base = t ? s[t - 1] : 0;
#pragma unroll
    for (int j = 0; j < 7; j++) {
        int i = t * 7 + j;
        if (i < NB) bstart[i] = base + loc[j];
    }
    if (t == 0) bstart[NB] = NE;
}

__global__ __launch_bounds__(256) void place_b(const int* __restrict__ ei, const float* __restrict__ ew,
                                               const int* __restrict__ bstart, const int* __restrict__ part,
                                               uint2* __restrict__ csr) {
    __shared__ int cur[NB];
    int chunk = blockIdx.x;
    const int* p = part + (size_t)chunk * NB;
    for (int i = threadIdx.x; i < NB; i += 256) cur[i] = bstart[i] + p[i];
    __syncthreads();
    int base = chunk * CHUNK;
    int lim = base + CHUNK; if (lim > NE) lim = NE;
    for (int e = base + threadIdx.x; e < lim; e += 256) {
        int s = ei[e], d = ei[NE + e];
        float w = ew[e];
        int pos = atomicAdd(&cur[d >> 6], 1);
        csr[pos] = make_uint2((uint)s | ((uint)(d & 63) << 17), __float_as_uint(w));
    }
}

__global__ __launch_bounds__(256) void subsort(uint2* __restrict__ csr, const int* __restrict__ bstart,
                                               int* __restrict__ row, float* __restrict__ dinv) {
    __shared__ uint2 E[CAP];
    __shared__ int cnt[64];
    __shared__ int cur[64];
    __shared__ float degf[64];
    int bkt = blockIdx.x;
    int beg = bstart[bkt], end = bstart[bkt + 1];
    int m = end - beg;
    if (threadIdx.x < 64) { cnt[threadIdx.x] = 0; degf[threadIdx.x] = 0.f; }
    __syncthreads();
    for (int i = threadIdx.x; i < m; i += 256) {
        uint2 ed = csr[beg + i];
        if (i < CAP) E[i] = ed;
        int dl = (ed.x >> 17) & 63;
        atomicAdd(&cnt[dl], 1);
        atomicAdd(&degf[dl], __uint_as_float(ed.y));
    }
    __syncthreads();
    if (threadIdx.x < 64) {
        int p = 0;
        for (int j = 0; j < (int)threadIdx.x; j++) p += cnt[j];
        cur[threadIdx.x] = p;
        int node = bkt * 64 + threadIdx.x;
        if (node < NN) {
            row[node] = beg + p;
            dinv[node] = rsqrtf(degf[threadIdx.x] + 1.0f);
        }
        if (bkt == NB - 1 && threadIdx.x == 0) row[NN] = NE;
    }
    __syncthreads();
    for (int i = threadIdx.x; i < m; i += 256) {
        uint2 ed = E[i < CAP ? i : 0];
        int dl = (ed.x >> 17) & 63;
        int pos = atomicAdd(&cur[dl], 1);
        csr[beg + pos] = make_uint2(ed.x & 0x1FFFFu, ed.y);
    }
}

__global__ __launch_bounds__(256) void norm_csr(uint2* __restrict__ csr, const int* __restrict__ row,
                                                const float* __restrict__ dinv, int n) {
    int wave = threadIdx.x >> 6, lane = threadIdx.x & 63;
    int node = blockIdx.x * 4 + wave;
    if (node >= n) return;
    int beg = row[node], end = row[node + 1];
    float di = dinv[node];
    for (int e = beg + lane; e < end; e += 64) {
        uint2 u = csr[e];
        csr[e].y = __float_as_uint(__uint_as_float(u.y) * dinv[u.x] * di);
    }
}

// ---------------- weight pre-pack into MFMA B-fragment layout ----------------

__global__ __launch_bounds__(256) void pack_w(const float* __restrict__ W, ushort* __restrict__ WF, int ncol) {
    int slot = blockIdx.x * 256 + threadIdx.x;
    int nc16 = ncol >> 4;
    int tot = 4 * nc16 * 64;
    if (slot >= tot) return;
    int lane = slot & 63;
    int c = (slot >> 6) % nc16;
    int ks = (slot >> 6) / nc16;
    int col = c * 16 + (lane & 15);
    int k0 = ks * 32 + (lane >> 4) * 8;
#pragma unroll
    for (int e = 0; e < 8; e++) WF[slot * 8 + e] = f2b(W[(k0 + e) * ncol + col]);
}

// ---------------- GEMM via MFMA: C[n,128] = A[n,128] @ W ----------------

template <bool AF32>
__global__ __launch_bounds__(256) void gemm_mfma(const void* __restrict__ Ap, const ushort* __restrict__ WF,
                                                 ushort* __restrict__ C, int ngrp) {
    __shared__ ushort Bl[4 * 8 * 64 * 8];  // 32 KB
    for (int i = threadIdx.x * 8; i < 4 * 8 * 64 * 8; i += 256 * 8)
        *(bf16x8*)&Bl[i] = *(const bf16x8*)&WF[i];
    __syncthreads();
    int wave = __builtin_amdgcn_readfirstlane(threadIdx.x >> 6);
    int lane = threadIdx.x & 63;
    int rg = blockIdx.x * 4 + wave;
    if (rg >= ngrp) return;
    int r0 = rg * 16;
    int rA = r0 + (lane & 15);
    int kb = (lane >> 4) * 8;
    bf16x8 a[4];
    if (AF32) {
        const float* A = (const float*)Ap;
#pragma unroll
        for (int ks = 0; ks < 4; ks++) {
            const float* p = &A[(size_t)rA * 128 + ks * 32 + kb];
            float4 x0 = *(const float4*)p;
            float4 x1 = *(const float4*)(p + 4);
            ushort t[8] = {f2b(x0.x), f2b(x0.y), f2b(x0.z), f2b(x0.w),
                           f2b(x1.x), f2b(x1.y), f2b(x1.z), f2b(x1.w)};
            a[ks] = *(bf16x8*)t;
        }
    } else {
        const ushort* A = (const ushort*)Ap;
#pragma unroll
        for (int ks = 0; ks < 4; ks++)
            a[ks] = *(const bf16x8*)&A[(size_t)rA * 128 + ks * 32 + kb];
    }
#pragma unroll
    for (int c = 0; c < 8; c++) {
        f32x4 acc = {0.f, 0.f, 0.f, 0.f};
#pragma unroll
        for (int ks = 0; ks < 4; ks++) {
            bf16x8 b = *(const bf16x8*)&Bl[((ks * 8 + c) * 64 + lane) * 8];
            acc = __builtin_amdgcn_mfma_f32_16x16x32_bf16(a[ks], b, acc, 0, 0, 0);
        }
        int colb = c * 16 + (lane & 15);
        int rowb = r0 + (lane >> 4) * 4;
#pragma unroll
        for (int r = 0; r < 4; r++)
            C[(size_t)(rowb + r) * 128 + colb] = f2b(acc[r]);
    }
}

// layer-2 GEMM with fused BN-affine + ReLU on A; emits H1 and C = H1 @ W2
__global__ __launch_bounds__(256) void gemm_mfma_bn(const ushort* __restrict__ HB, const float* __restrict__ stats,
                                                    const ushort* __restrict__ WF, ushort* __restrict__ H1,
                                                    ushort* __restrict__ C, int ngrp) {
    __shared__ ushort Bl[4 * 8 * 64 * 8];  // 32 KB
    __shared__ float sst[256];
    sst[threadIdx.x] = stats[threadIdx.x];
    for (int i = threadIdx.x * 8; i < 4 * 8 * 64 * 8; i += 256 * 8)
        *(bf16x8*)&Bl[i] = *(const bf16x8*)&WF[i];
    __syncthreads();
    int wave = __builtin_amdgcn_readfirstlane(threadIdx.x >> 6);
    int lane = threadIdx.x & 63;
    int rg = blockIdx.x * 4 + wave;
    if (rg >= ngrp) return;
    int r0 = rg * 16;
    int rA = r0 + (lane & 15);
    int kb = (lane >> 4) * 8;
    bf16x8 a[4];
#pragma unroll
    for (int ks = 0; ks < 4; ks++) {
        int cbase = ks * 32 + kb;
        bf16x8 u = *(const bf16x8*)&HB[(size_t)rA * 128 + cbase];
        ushort t[8];
#pragma unroll
        for (int e = 0; e < 8; e++) {
            float f = fmaxf(b2f((ushort)u[e]) * sst[cbase + e] + sst[128 + cbase + e], 0.f);
            t[e] = f2b(f);
        }
        a[ks] = *(bf16x8*)t;
        *(bf16x8*)&H1[(size_t)rA * 128 + cbase] = a[ks];
    }
#pragma unroll
    for (int c = 0; c < 8; c++) {
        f32x4 acc = {0.f, 0.f, 0.f, 0.f};
#pragma unroll
        for (int ks = 0; ks < 4; ks++) {
            bf16x8 b = *(const bf16x8*)&Bl[((ks * 8 + c) * 64 + lane) * 8];
            acc = __builtin_amdgcn_mfma_f32_16x16x32_bf16(a[ks], b, acc, 0, 0, 0);
        }
        int colb = c * 16 + (lane & 15);
        int rowb = r0 + (lane >> 4) * 4;
#pragma unroll
        for (int r = 0; r < 4; r++)
            C[(size_t)(rowb + r) * 128 + colb] = f2b(acc[r]);
    }
}

// ---------------- final: OUT[n,64] = max(H1,H2) @ Wf + bf (MFMA) ----------------

__global__ __launch_bounds__(256) void final_mfma(const ushort* __restrict__ H1, const ushort* __restrict__ H2,
                                                  const ushort* __restrict__ WF, const float* __restrict__ bfv,
                                                  float* __restrict__ OUT, int ngrp) {
    __shared__ ushort Bl[4 * 4 * 64 * 8];  // 16 KB
    for (int i = threadIdx.x * 8; i < 4 * 4 * 64 * 8; i += 256 * 8)
        *(bf16x8*)&Bl[i] = *(const bf16x8*)&WF[i];
    __syncthreads();
    int wave = __builtin_amdgcn_readfirstlane(threadIdx.x >> 6);
    int lane = threadIdx.x & 63;
    int rg = blockIdx.x * 4 + wave;
    if (rg >= ngrp) return;
    int r0 = rg * 16;
    int rA = r0 + (lane & 15);
    int kb = (lane >> 4) * 8;
    bf16x8 a[4];
#pragma unroll
    for (int ks = 0; ks < 4; ks++) {
        bf16x8 u = *(const bf16x8*)&H1[(size_t)rA * 128 + ks * 32 + kb];
        bf16x8 v = *(const bf16x8*)&H2[(size_t)rA * 128 + ks * 32 + kb];
        ushort t[8];
#pragma unroll
        for (int e = 0; e < 8; e++) {
            ushort ue = (ushort)u[e], ve = (ushort)v[e];
            t[e] = (b2f(ue) >= b2f(ve)) ? ue : ve;
        }
        a[ks] = *(bf16x8*)t;
    }
#pragma unroll
    for (int c = 0; c < 4; c++) {
        f32x4 acc = {0.f, 0.f, 0.f, 0.f};
#pragma unroll
        for (int ks = 0; ks < 4; ks++) {
            bf16x8 b = *(const bf16x8*)&Bl[((ks * 4 + c) * 64 + lane) * 8];
            acc = __builtin_amdgcn_mfma_f32_16x16x32_bf16(a[ks], b, acc, 0, 0, 0);
        }
        int colb = c * 16 + (lane & 15);
        int rowb = r0 + (lane >> 4) * 4;
        float bb = bfv[colb];
#pragma unroll
        for (int r = 0; r < 4; r++)
            OUT[(size_t)(rowb + r) * 64 + colb] = acc[r] + bb;
    }
}

// ---------------- aggregation (bf16 features, fp32 accum, unroll-4) ----------------

__global__ __launch_bounds__(256) void aggregate_b2(const ushort* __restrict__ XW, const int* __restrict__ row,
                                                    const uint2* __restrict__ csr, const float* __restrict__ dinv,
                                                    const float* __restrict__ bias, ushort* __restrict__ OUT, int n) {
    int wave = __builtin_amdgcn_readfirstlane(threadIdx.x >> 6);
    int lane = threadIdx.x & 63;
    int node = blockIdx.x * 4 + wave;
    if (node >= n) return;
    int beg = row[node], end = row[node + 1];
    float ax = 0.f, ay = 0.f;
    int e = beg;
    for (; e + 3 < end; e += 4) {
        uint2 p0 = csr[e], p1 = csr[e + 1], p2 = csr[e + 2], p3 = csr[e + 3];
        uint v0 = *(const uint*)&XW[(size_t)p0.x * 128 + lane * 2];
        uint v1 = *(const uint*)&XW[(size_t)p1.x * 128 + lane * 2];
        uint v2 = *(const uint*)&XW[(size_t)p2.x * 128 + lane * 2];
        uint v3 = *(const uint*)&XW[(size_t)p3.x * 128 + lane * 2];
        float w0 = __uint_as_float(p0.y), w1 = __uint_as_float(p1.y);
        float w2 = __uint_as_float(p2.y), w3 = __uint_as_float(p3.y);
        ax += w0 * __uint_as_float(v0 << 16) + w1 * __uint_as_float(v1 << 16) +
              w2 * __uint_as_float(v2 << 16) + w3 * __uint_as_float(v3 << 16);
        ay += w0 * __uint_as_float(v0 & 0xFFFF0000u) + w1 * __uint_as_float(v1 & 0xFFFF0000u) +
              w2 * __uint_as_float(v2 & 0xFFFF0000u) + w3 * __uint_as_float(v3 & 0xFFFF0000u);
    }
    for (; e < end; e++) {
        uint2 p0 = csr[e];
        float w0 = __uint_as_float(p0.y);
        uint v0 = *(const uint*)&XW[(size_t)p0.x * 128 + lane * 2];
        ax += w0 * __uint_as_float(v0 << 16);
        ay += w0 * __uint_as_float(v0 & 0xFFFF0000u);
    }
    float di = dinv[node], sl = di * di;
    uint vs = *(const uint*)&XW[(size_t)node * 128 + lane * 2];
    float ox = ax + sl * __uint_as_float(vs << 16) + bias[lane * 2];
    float oy = ay + sl * __uint_as_float(vs & 0xFFFF0000u) + bias[lane * 2 + 1];
    uint o = (uint)f2b(ox) | ((uint)f2b(oy) << 16);
    *(uint*)&OUT[(size_t)node * 128 + lane * 2] = o;
}

// ---------------- BatchNorm stats ----------------

__global__ __launch_bounds__(256) void bn_stats_b(const ushort* __restrict__ H, float* __restrict__ part, int n) {
    int wave = threadIdx.x >> 6;
    int lane = threadIdx.x & 63;
    float2 s = make_float2(0.f, 0.f), q = make_float2(0.f, 0.f);
    for (int r = blockIdx.x * 4 + wave; r < n; r += gridDim.x * 4) {
        uint v = *(const uint*)&H[(size_t)r * 128 + lane * 2];
        float x = __uint_as_float(v << 16);
        float y = __uint_as_float(v & 0xFFFF0000u);
        s.x += x; s.y += y;
        q.x += x * x; q.y += y * y;
    }
    __shared__ float2 reds[4][64];
    __shared__ float2 redq[4][64];
    reds[wave][lane] = s;
    redq[wave][lane] = q;
    __syncthreads();
    if (threadIdx.x < 64) {
        int l = threadIdx.x;
        float2 S = make_float2(0.f, 0.f), Q = make_float2(0.f, 0.f);
#pragma unroll
        for (int w = 0; w < 4; w++) {
            S.x += reds[w][l].x; S.y += reds[w][l].y;
            Q.x += redq[w][l].x; Q.y += redq[w][l].y;
        }
        part[blockIdx.x * 256 + l * 2 + 0] = S.x;
        part[blockIdx.x * 256 + l * 2 + 1] = S.y;
        part[blockIdx.x * 256 + 128 + l * 2 + 0] = Q.x;
        part[blockIdx.x * 256 + 128 + l * 2 + 1] = Q.y;
    }
}

// parallel final reduction: 1024 threads = 128 channels x 8 groups, unrolled
__global__ __launch_bounds__(1024) void bn_final2(const float* __restrict__ part, const float* __restrict__ gamma,
                                                  const float* __restrict__ beta, float* __restrict__ stats,
                                                  float invN) {
    int c = threadIdx.x & 127;   // channel
    int g = threadIdx.x >> 7;    // group 0..7
    float s = 0.f, q = 0.f;
#pragma unroll 8
    for (int b = g; b < 512; b += 8) {
        s += part[b * 256 + c];
        q += part[b * 256 + 128 + c];
    }
    __shared__ float red[8][256];
    red[g][c] = s;
    red[g][128 + c] = q;
    __syncthreads();
    __shared__ float fin[256];
    if (threadIdx.x < 256) {
        float acc = 0.f;
#pragma unroll
        for (int gg = 0; gg < 8; gg++) acc += red[gg][threadIdx.x];
        fin[threadIdx.x] = acc;
    }
    __syncthreads();
    if (threadIdx.x < 128) {
        float mu = fin[c] * invN;
        float var = fin[128 + c] * invN - mu * mu;
        float sc = gamma[c] * rsqrtf(var + EPSF);
        stats[c] = sc;
        stats[128 + c] = beta[c] - mu * sc;
    }
}

// ---------------- launch ----------------

extern "C" void kernel_launch(void* const* d_in, const int* in_sizes, int n_in,
                              void* d_out, int out_size, void* d_ws, size_t ws_size,
                              hipStream_t stream) {
    const float* x     = (const float*)d_in[0];
    const int*   ei    = (const int*)  d_in[1];
    const float* ew    = (const float*)d_in[2];
    const float* W1    = (const float*)d_in[3];
    const float* b1    = (const float*)d_in[4];
    const float* gamma = (const float*)d_in[5];
    const float* beta  = (const float*)d_in[6];
    const float* W2    = (const float*)d_in[7];
    const float* b2    = (const float*)d_in[8];
    const float* Wf    = (const float*)d_in[9];
    const float* bf    = (const float*)d_in[10];
    float* out = (float*)d_out;

    char* ws = (char*)d_ws;
    size_t off = 0;
    auto alloc = [&](size_t bytes) {
        void* p = ws + off;
        off += (bytes + 1023) & ~(size_t)1023;
        return p;
    };
    ushort* XWB  = (ushort*)alloc((size_t)NN * 128 * 2);
    ushort* HB   = (ushort*)alloc((size_t)NN * 128 * 2);
    ushort* H1B  = (ushort*)alloc((size_t)NN * 128 * 2);
    ushort* H2B  = (ushort*)alloc((size_t)NN * 128 * 2);
    float*  DINV = (float*) alloc((size_t)NN * 4);
    int*    ROW  = (int*)   alloc((size_t)(NN + 1) * 4);
    int*    CNT  = (int*)   alloc((size_t)NB * 4);
    int*    BSTART = (int*) alloc((size_t)(NB + 1) * 4);
    uint2*  CSR8 = (uint2*) alloc((size_t)NE * 8);
    float*  PARTBN = (float*)alloc((size_t)512 * 256 * 4);
    float*  STAT = (float*) alloc(1024);
    ushort* WF1  = (ushort*)alloc((size_t)4 * 8 * 64 * 8 * 2);
    ushort* WF2  = (ushort*)alloc((size_t)4 * 8 * 64 * 8 * 2);
    ushort* WFF  = (ushort*)alloc((size_t)4 * 4 * 64 * 8 * 2);
    int* PART = (int*)XWB;   // 1.6 MB alias, used only pre-GEMM

    int ngrp = NN / 16;               // 6250
    int gblocks = (ngrp + 3) / 4;     // 1563

    // ---- two-level counting sort (bucket=node>>6), zero global atomics ----
    hist_b<<<NCHUNK, 256, 0, stream>>>(ei, PART);
    scan_chunks_b<<<(NB + 255) / 256, 256, 0, stream>>>(PART, CNT);
    bucket_scan<<<1, 256, 0, stream>>>(CNT, BSTART);
    place_b<<<NCHUNK, 256, 0, stream>>>(ei, ew, BSTART, PART, CSR8);
    subsort<<<NB, 256, 0, stream>>>(CSR8, BSTART, ROW, DINV);
    norm_csr<<<(NN + 3) / 4, 256, 0, stream>>>(CSR8, ROW, DINV, NN);

    pack_w<<<8, 256, 0, stream>>>(W1, WF1, 128);
    pack_w<<<8, 256, 0, stream>>>(W2, WF2, 128);
    pack_w<<<4, 256, 0, stream>>>(Wf, WFF, 64);

    // layer 1
    gemm_mfma<true><<<gblocks, 256, 0, stream>>>(x, WF1, XWB, ngrp);
    aggregate_b2<<<(NN + 3) / 4, 256, 0, stream>>>(XWB, ROW, CSR8, DINV, b1, HB, NN);
    bn_stats_b<<<512, 256, 0, stream>>>(HB, PARTBN, NN);
    bn_final2<<<1, 1024, 0, stream>>>(PARTBN, gamma, beta, STAT, 1.0f / NN);

    // layer 2 (BN+ReLU fused into A-load; emits H1B and XWB = H1 @ W2)
    gemm_mfma_bn<<<gblocks, 256, 0, stream>>>(HB, STAT, WF2, H1B, XWB, ngrp);
    aggregate_b2<<<(NN + 3) / 4, 256, 0, stream>>>(XWB, ROW, CSR8, DINV, b2, H2B, NN);

    // JK max + final projection
    final_mfma<<<gblocks, 256, 0, stream>>>(H1B, H2B, WFF, bf, out, ngrp);
}